// Round 9
// baseline (393.925 us; speedup 1.0000x reference)
//
#include <hip/hip_runtime.h>
#include <hip/hip_bf16.h>
#include <math.h>

#define NH    8
#define CPH   48
#define D     384
#define QC    1152
#define HF    192
#define WFULL 192
#define HP    96
#define WP    96
#define NP    9216    // 96*96
#define NF    36864   // 192*192

typedef __attribute__((ext_vector_type(8))) short short8;
typedef __attribute__((ext_vector_type(4))) float f32x4;

__device__ __forceinline__ float gelu_exact(float v) {
    return 0.5f * v * (1.f + erff(v * 0.70710678118654752440f));
}
__device__ __forceinline__ ushort f2bf(float v) {
    __hip_bfloat16 h = __float2bfloat16(v);
    return *reinterpret_cast<ushort*>(&h);
}
__device__ __forceinline__ float bf2f(ushort u) {
    __hip_bfloat16 h = *reinterpret_cast<__hip_bfloat16*>(&u);
    return __bfloat162float(h);
}

// ---------------- P1: split fp32 -> bf16 hi/lo (wp; AFTER dwconv: its dest ---
// lives in the pooled region, which is dead only once dwconv has read it) ----
__global__ __launch_bounds__(256) void k_prep_w(
    const float* __restrict__ w, ushort* __restrict__ wh, ushort* __restrict__ wl, int n) {
    int i = blockIdx.x * 256 + threadIdx.x;
    if (i < n) {
        float v = w[i];
        ushort h = f2bf(v);
        wh[i] = h;
        wl[i] = f2bf(v - bf2f(h));
    }
}

// ---------------- P2 (fused): wq split + x split/transpose -------------------
// blocks [0,1728): wq -> wh/wl.  blocks [1728,3456): x -> xh/xl in
// n' = (py*96+px)*4 + (y&1)*2 + (x&1) pool-quad-contiguous pixel order.
__global__ __launch_bounds__(256) void k_prep(
    const float* __restrict__ wq, ushort* __restrict__ wh, ushort* __restrict__ wl,
    const float* __restrict__ x, ushort* __restrict__ xh, ushort* __restrict__ xl) {
    __shared__ float xf[64][128];   // 32 KB (unused by w-branch)
    const int tid = threadIdx.x;
    if (blockIdx.x < 1728) {
        int i = blockIdx.x * 256 + tid;          // 442368 = 1728*256 exact
        float v = wq[i];
        ushort h = f2bf(v);
        wh[i] = h;
        wl[i] = f2bf(v - bf2f(h));
        return;
    }
    const int e  = blockIdx.x - 1728;
    const int xt = e % 288, kt = e / 288;
    const int kk = kt * 64;
    const int q0 = xt * 32;                  // 32 pool quads (one pool row chunk)
    const int py = q0 / 96, px0 = q0 - py * 96;
    const int y0 = 2 * py, xcol0 = 2 * px0;
    const float* xb = x + (size_t)kk * NF + (size_t)y0 * WFULL + xcol0;
#pragma unroll
    for (int it = 0; it < 8; it++) {
        int li = tid + 256 * it;
        int ch = li >> 5, r = (li >> 4) & 1, c4 = (li & 15) * 4;
        float4 v = *(const float4*)&xb[(size_t)ch * NF + r * WFULL + c4];
        *(float4*)&xf[ch][r * 64 + c4] = v;
    }
    __syncthreads();
    const int row = tid >> 1, half = tid & 1;
    const int r = (row >> 1) & 1;
    const int col = (row >> 2) * 2 + (row & 1);
    const int src = r * 64 + col;
    const size_t np = (size_t)xt * 128 + row;
    ushort hbuf[32], lbuf[32];
#pragma unroll
    for (int j = 0; j < 32; j++) {
        float v = xf[half * 32 + j][src];
        ushort h = f2bf(v);
        hbuf[j] = h;
        lbuf[j] = f2bf(v - bf2f(h));
    }
    ushort* dh = xh + np * D + kk + half * 32;
    ushort* dl = xl + np * D + kk + half * 32;
#pragma unroll
    for (int j = 0; j < 4; j++) {
        *(short8*)&dh[j * 8] = *(const short8*)&hbuf[j * 8];
        *(short8*)&dl[j * 8] = *(const short8*)&lbuf[j * 8];
    }
}

// ---------------- K1: qkv 1x1 conv as bf16x3 MFMA GEMM + fused 2x2 maxpool ---
// Split into two half-M launches (mbase = 0 / 144) for per-kernel visibility.
__global__ __launch_bounds__(256) void k_qkv_mfma(
    const ushort* __restrict__ xh, const ushort* __restrict__ xl,
    const ushort* __restrict__ wh, const ushort* __restrict__ wl,
    const float* __restrict__ bq, float* __restrict__ pooled, int mbase) {
    __shared__ ushort lds[2][4][4096];  // [buf][Ah,Al,Bh,Bl][128 rows x 32 bf16]
    const int tid = threadIdx.x;
    const int lane = tid & 63, wid = tid >> 6;
    const int wm = wid >> 1, wn = wid & 1;

    const int d   = blockIdx.x;        // 0..1295, HW XCD = d % 8
    const int xcd = d & 7;
    const int idx = d >> 3;            // 0..161
    const int by  = mbase + xcd * 18 + idx / 9;
    const int bx  = idx % 9;
    const int n0 = bx * 128;
    const int m0 = by * 128;

    const ushort* srcs[4];
    srcs[0] = xh + (size_t)m0 * D;
    srcs[1] = xl + (size_t)m0 * D;
    srcs[2] = wh + (size_t)n0 * D;
    srcs[3] = wl + (size_t)n0 * D;

    f32x4 acc[4][4];
#pragma unroll
    for (int i = 0; i < 4; i++)
#pragma unroll
        for (int j = 0; j < 4; j++) acc[i][j] = (f32x4){0.f, 0.f, 0.f, 0.f};

    int a_off[4], b_off[4];
#pragma unroll
    for (int f = 0; f < 4; f++) {
        int ra = wm * 64 + f * 16 + (lane & 15);
        a_off[f] = ra * 64 + ((((lane >> 4) ^ ((ra >> 1) & 3)) & 3) << 4);
        int rb = wn * 64 + f * 16 + (lane & 15);
        b_off[f] = rb * 64 + ((((lane >> 4) ^ ((rb >> 1) & 3)) & 3) << 4);
    }

    auto STAGE = [&](int buf, int kk) {
#pragma unroll
        for (int i = 0; i < 8; i++) {
            const int mat = i >> 1;
            const int cm  = ((i & 1) << 2) | wid;
            const int row = cm * 16 + (lane >> 2);
            const int scol = (((lane & 3) ^ ((row >> 1) & 3)) & 3) << 4;
            const ushort* src = srcs[mat] + (size_t)row * D + kk + (scol >> 1);
            __builtin_amdgcn_global_load_lds(
                (const __attribute__((address_space(1))) void*)src,
                (__attribute__((address_space(3))) void*)&lds[buf][mat][cm * 512],
                16, 0, 0);
        }
    };

    STAGE(0, 0);
    for (int t = 0; t < 12; ++t) {
        const int cur = t & 1;
        if (t < 11) {
            STAGE(cur ^ 1, (t + 1) * 32);
            asm volatile("s_waitcnt vmcnt(8)" ::: "memory");
        } else {
            asm volatile("s_waitcnt vmcnt(0)" ::: "memory");
        }
        __builtin_amdgcn_s_barrier();

        const char* bA0 = (const char*)&lds[cur][0][0];
        const char* bA1 = (const char*)&lds[cur][1][0];
        const char* bB0 = (const char*)&lds[cur][2][0];
        const char* bB1 = (const char*)&lds[cur][3][0];
        short8 A[2][4], B[2][4];
#pragma unroll
        for (int f = 0; f < 4; f++) {
            A[0][f] = *(const short8*)(bA0 + a_off[f]);
            A[1][f] = *(const short8*)(bA1 + a_off[f]);
            B[0][f] = *(const short8*)(bB0 + b_off[f]);
            B[1][f] = *(const short8*)(bB1 + b_off[f]);
        }
        __builtin_amdgcn_s_setprio(1);
#pragma unroll
        for (int fm = 0; fm < 4; fm++)
#pragma unroll
            for (int fn = 0; fn < 4; fn++) {
                acc[fm][fn] = __builtin_amdgcn_mfma_f32_16x16x32_bf16(A[0][fm], B[0][fn], acc[fm][fn], 0, 0, 0);
                acc[fm][fn] = __builtin_amdgcn_mfma_f32_16x16x32_bf16(A[0][fm], B[1][fn], acc[fm][fn], 0, 0, 0);
                acc[fm][fn] = __builtin_amdgcn_mfma_f32_16x16x32_bf16(A[1][fm], B[0][fn], acc[fm][fn], 0, 0, 0);
            }
        __builtin_amdgcn_s_setprio(0);
        asm volatile("s_waitcnt lgkmcnt(0)" ::: "memory");
        __builtin_amdgcn_s_barrier();
    }

    const int p_base = by * 32 + wm * 16 + (lane >> 4);
#pragma unroll
    for (int fn = 0; fn < 4; fn++) {
        const int o = n0 + wn * 64 + fn * 16 + (lane & 15);
        const float b = bq[o];
#pragma unroll
        for (int fm = 0; fm < 4; fm++) {
            f32x4 v = acc[fm][fn];
            float mx = fmaxf(fmaxf(v.x, v.y), fmaxf(v.z, v.w)) + b;
            pooled[(size_t)o * NP + p_base + fm * 4] = mx;
        }
    }
}

// ---------------- K2: depthwise 3x3 conv, vectorized 4 outputs/thread --------
__global__ __launch_bounds__(256) void k_dwconv(
    const float* __restrict__ pooled, const float* __restrict__ wd,
    const float* __restrict__ bd, float* __restrict__ out) {
    int gid = blockIdx.x * 256 + threadIdx.x;   // 0 .. 2,654,207
    int xq = gid % 24, t = gid / 24;
    int y = t % 96, ch = t / 96;                // ch uniform per block (2304/ch)
    const float* src = pooled + (size_t)ch * NP;
    const float* w = wd + ch * 9;
    const int x0 = xq * 4;
    float b = bd[ch];
    float o0 = b, o1 = b, o2 = b, o3 = b;
#pragma unroll
    for (int dy = 0; dy < 3; dy++) {
        int yy = y + dy - 1;
        if (yy < 0 || yy >= HP) continue;
        const float* r = src + yy * WP;
        float4 c = *(const float4*)&r[x0];
        float lm = (x0 > 0) ? r[x0 - 1] : 0.f;
        float rm = (x0 < 92) ? r[x0 + 4] : 0.f;
        float w0 = w[dy * 3], w1 = w[dy * 3 + 1], w2 = w[dy * 3 + 2];
        o0 += w0 * lm  + w1 * c.x + w2 * c.y;
        o1 += w0 * c.x + w1 * c.y + w2 * c.z;
        o2 += w0 * c.y + w1 * c.z + w2 * c.w;
        o3 += w0 * c.z + w1 * c.w + w2 * rm;
    }
    *(float4*)&out[(size_t)ch * NP + y * WP + x0] = make_float4(o0, o1, o2, o3);
}

// ---------------- K3a: attn partials, no atomics -----------------------------
__global__ __launch_bounds__(256) void k_attn_part(
    const float* __restrict__ qkv, float* __restrict__ Spart,
    float* __restrict__ qnpart, float* __restrict__ knpart) {
    __shared__ float qs[48][196], ks[48][196];
    const int tid = threadIdx.x;
    const int p = blockIdx.x, h = blockIdx.y;
    const int n0 = p * 192;
    const float* qb = qkv + (size_t)(h * CPH) * NP + n0;
    const float* kb = qkv + (size_t)(D + h * CPH) * NP + n0;
#pragma unroll
    for (int it = 0; it < 9; it++) {
        int li = tid + 256 * it;             // 0..2303 float4s
        int row = li / 48, c4 = (li - row * 48) * 4;
        *(float4*)&qs[row][c4] = *(const float4*)&qb[(size_t)row * NP + c4];
        *(float4*)&ks[row][c4] = *(const float4*)&kb[(size_t)row * NP + c4];
    }
    __syncthreads();
    const int tr = (tid >> 4) * 3, tc = (tid & 15) * 3;
    float acc[3][3] = {};
    for (int n = 0; n < 192; n++) {
        float qv[3], kv[3];
#pragma unroll
        for (int i = 0; i < 3; i++) qv[i] = qs[tr + i][n];
#pragma unroll
        for (int j = 0; j < 3; j++) kv[j] = ks[tc + j][n];
#pragma unroll
        for (int i = 0; i < 3; i++)
#pragma unroll
            for (int j = 0; j < 3; j++) acc[i][j] += qv[i] * kv[j];
    }
    float* Sp = Spart + (size_t)(p * NH + h) * 2304;
#pragma unroll
    for (int i = 0; i < 3; i++)
#pragma unroll
        for (int j = 0; j < 3; j++)
            Sp[(tr + i) * CPH + tc + j] = acc[i][j];
    if (tid < 48) {
        float s = 0.f;
        for (int n = 0; n < 192; n++) s += qs[tid][n] * qs[tid][n];
        qnpart[(p * NH + h) * CPH + tid] = s;
    } else if (tid >= 64 && tid < 112) {
        int t2 = tid - 64;
        float s = 0.f;
        for (int n = 0; n < 192; n++) s += ks[t2][n] * ks[t2][n];
        knpart[(p * NH + h) * CPH + t2] = s;
    }
}

// ---------------- K4 (fused red+softmax): partials -> Wc ---------------------
__global__ __launch_bounds__(256) void k_softmax(
    const float* __restrict__ Spart, const float* __restrict__ qnpart,
    const float* __restrict__ knpart, const float* __restrict__ temp,
    const float* __restrict__ a1, const float* __restrict__ a2,
    const float* __restrict__ a3, const float* __restrict__ a4,
    float* __restrict__ Wc) {
    __shared__ float rowbuf[4][64];
    int lane = threadIdx.x & 63;
    int w = threadIdx.x >> 6;
    int row = blockIdx.x * 4 + w;
    int h = row / CPH, c = row % CPH;
    float a = -INFINITY;
    if (lane < CPH) {
        float s = 0.f, q2 = 0.f, k2 = 0.f;
        for (int p = 0; p < 48; p++) {
            int base = (p * NH + h);
            s  += Spart[(size_t)base * 2304 + c * CPH + lane];
            q2 += qnpart[base * CPH + c];
            k2 += knpart[base * CPH + lane];
        }
        float nq = fmaxf(sqrtf(fmaxf(q2, 0.f)), 1e-12f);
        float nk = fmaxf(sqrtf(fmaxf(k2, 0.f)), 1e-12f);
        a = s / (nq * nk) * temp[h];
    }
    rowbuf[w][lane] = a;
    __syncthreads();
    int rank = 0;
    float m = -INFINITY;
    for (int j = 0; j < CPH; j++) {
        float vj = rowbuf[w][j];
        m = fmaxf(m, vj);
        rank += (vj > a || (vj == a && j < lane)) ? 1 : 0;
    }
    float e = (lane < CPH) ? expf(a - m) : 0.f;
    float4 p;
    p.x = (rank < 24) ? e : 0.f;
    p.y = (rank < 32) ? e : 0.f;
    p.z = (rank < 36) ? e : 0.f;
    p.w = (rank < 38) ? e : 0.f;
#pragma unroll
    for (int off = 32; off > 0; off >>= 1) {
        p.x += __shfl_xor(p.x, off);
        p.y += __shfl_xor(p.y, off);
        p.z += __shfl_xor(p.z, off);
        p.w += __shfl_xor(p.w, off);
    }
    if (lane < CPH) {
        float wv = 0.f;
        if (rank < 24) wv += a1[0] / p.x;
        if (rank < 32) wv += a2[0] / p.y;
        if (rank < 36) wv += a3[0] / p.z;
        if (rank < 38) wv += a4[0] / p.w;
        Wc[(h * CPH + c) * CPH + lane] = e * wv;
    }
}

// ---------------- K5: gelu(Wc @ v) -> bf16 hi/lo rows [n][384] ---------------
// 1 thread = 1 px x 16 ch (no spill), 864 blocks (8h x 3thirds x 36 chunks).
__global__ __launch_bounds__(256) void k_av_gelu(
    const float* __restrict__ qkv, const float* __restrict__ Wc,
    ushort* __restrict__ o96h, ushort* __restrict__ o96l) {
    __shared__ float Ws[48][16];   // 3 KB slice of W^T for this (head, third)
    const int tid = threadIdx.x;
    const int b = blockIdx.x;          // h(8) x third(3) x chunk(36)
    const int h = b / 108;
    const int rem = b - h * 108;
    const int t3 = rem / 36;
    const int pc = rem - t3 * 36;
    const int c0 = t3 * 16;
    const int px = pc * 256 + tid;
    for (int li = tid; li < 768; li += 256) {
        int dd = li >> 4, cc = li & 15;
        Ws[dd][cc] = Wc[(h * CPH + c0 + cc) * CPH + dd];
    }
    __syncthreads();
    const float* vb = qkv + (size_t)(2 * D + h * CPH) * NP + px;
    float acc[16] = {};
#pragma unroll
    for (int dd = 0; dd < 48; dd++) {
        float vv = vb[(size_t)dd * NP];
#pragma unroll
        for (int c4 = 0; c4 < 4; c4++) {
            float4 w = *(const float4*)&Ws[dd][c4 * 4];
            acc[c4 * 4 + 0] += w.x * vv;
            acc[c4 * 4 + 1] += w.y * vv;
            acc[c4 * 4 + 2] += w.z * vv;
            acc[c4 * 4 + 3] += w.w * vv;
        }
    }
    short8 hv0, hv1, lv0, lv1;
#pragma unroll
    for (int j = 0; j < 8; j++) {
        float g = gelu_exact(acc[j]);
        ushort hu = f2bf(g);
        hv0[j] = (short)hu; lv0[j] = (short)f2bf(g - bf2f(hu));
        float g2 = gelu_exact(acc[8 + j]);
        ushort hu2 = f2bf(g2);
        hv1[j] = (short)hu2; lv1[j] = (short)f2bf(g2 - bf2f(hu2));
    }
    size_t base = (size_t)px * D + h * CPH + c0;
    *(short8*)&o96h[base] = hv0;
    *(short8*)&o96h[base + 8] = hv1;
    *(short8*)&o96l[base] = lv0;
    *(short8*)&o96l[base + 8] = lv1;
}

// ---------------- K6: proj 1x1 as bf16x3 MFMA + nearest 2x upsample ----------
__global__ __launch_bounds__(256) void k_proj_mfma(
    const ushort* __restrict__ wph, const ushort* __restrict__ wpl,
    const ushort* __restrict__ o96h, const ushort* __restrict__ o96l,
    const float* __restrict__ bp, float* __restrict__ out) {
    __shared__ ushort lds[2][4][4096];
    const int tid = threadIdx.x;
    const int lane = tid & 63, wid = tid >> 6;
    const int wm = wid >> 1, wn = wid & 1;

    const int d   = blockIdx.x;        // 0..215
    const int xcd = d & 7;
    const int idx = d >> 3;            // 0..26
    const int nt  = xcd * 9 + idx / 3; // n-tile 0..71
    const int ot  = idx % 3;           // o-tile 0..2
    const int o0 = ot * 128;
    const int n0 = nt * 128;

    const ushort* srcs[4];
    srcs[0] = wph + (size_t)o0 * D;
    srcs[1] = wpl + (size_t)o0 * D;
    srcs[2] = o96h + (size_t)n0 * D;
    srcs[3] = o96l + (size_t)n0 * D;

    f32x4 acc[4][4];
#pragma unroll
    for (int i = 0; i < 4; i++)
#pragma unroll
        for (int j = 0; j < 4; j++) acc[i][j] = (f32x4){0.f, 0.f, 0.f, 0.f};

    int a_off[4], b_off[4];
#pragma unroll
    for (int f = 0; f < 4; f++) {
        int ra = wm * 64 + f * 16 + (lane & 15);
        a_off[f] = ra * 64 + ((((lane >> 4) ^ ((ra >> 1) & 3)) & 3) << 4);
        int rb = wn * 64 + f * 16 + (lane & 15);
        b_off[f] = rb * 64 + ((((lane >> 4) ^ ((rb >> 1) & 3)) & 3) << 4);
    }

    auto STAGE = [&](int buf, int kk) {
#pragma unroll
        for (int i = 0; i < 8; i++) {
            const int mat = i >> 1;
            const int cm  = ((i & 1) << 2) | wid;
            const int row = cm * 16 + (lane >> 2);
            const int scol = (((lane & 3) ^ ((row >> 1) & 3)) & 3) << 4;
            const ushort* src = srcs[mat] + (size_t)row * D + kk + (scol >> 1);
            __builtin_amdgcn_global_load_lds(
                (const __attribute__((address_space(1))) void*)src,
                (__attribute__((address_space(3))) void*)&lds[buf][mat][cm * 512],
                16, 0, 0);
        }
    };

    STAGE(0, 0);
    for (int t = 0; t < 12; ++t) {
        const int cur = t & 1;
        if (t < 11) {
            STAGE(cur ^ 1, (t + 1) * 32);
            asm volatile("s_waitcnt vmcnt(8)" ::: "memory");
        } else {
            asm volatile("s_waitcnt vmcnt(0)" ::: "memory");
        }
        __builtin_amdgcn_s_barrier();

        const char* bA0 = (const char*)&lds[cur][0][0];
        const char* bA1 = (const char*)&lds[cur][1][0];
        const char* bB0 = (const char*)&lds[cur][2][0];
        const char* bB1 = (const char*)&lds[cur][3][0];
        short8 A[2][4], B[2][4];
#pragma unroll
        for (int f = 0; f < 4; f++) {
            A[0][f] = *(const short8*)(bA0 + a_off[f]);
            A[1][f] = *(const short8*)(bA1 + a_off[f]);
            B[0][f] = *(const short8*)(bB0 + b_off[f]);
            B[1][f] = *(const short8*)(bB1 + b_off[f]);
        }
        __builtin_amdgcn_s_setprio(1);
#pragma unroll
        for (int fm = 0; fm < 4; fm++)
#pragma unroll
            for (int fn = 0; fn < 4; fn++) {
                acc[fm][fn] = __builtin_amdgcn_mfma_f32_16x16x32_bf16(A[0][fm], B[0][fn], acc[fm][fn], 0, 0, 0);
                acc[fm][fn] = __builtin_amdgcn_mfma_f32_16x16x32_bf16(A[0][fm], B[1][fn], acc[fm][fn], 0, 0, 0);
                acc[fm][fn] = __builtin_amdgcn_mfma_f32_16x16x32_bf16(A[1][fm], B[0][fn], acc[fm][fn], 0, 0, 0);
            }
        __builtin_amdgcn_s_setprio(0);
        asm volatile("s_waitcnt lgkmcnt(0)" ::: "memory");
        __builtin_amdgcn_s_barrier();
    }

#pragma unroll
    for (int fn = 0; fn < 4; fn++) {
        const int n = n0 + wn * 64 + fn * 16 + (lane & 15);
        const int y = n / WP, xcol = n - y * WP;
        const size_t pbase = (size_t)(2 * y) * WFULL + 2 * xcol;
#pragma unroll
        for (int fm = 0; fm < 4; fm++) {
            f32x4 v = acc[fm][fn];
#pragma unroll
            for (int j = 0; j < 4; j++) {
                const int o = o0 + wm * 64 + fm * 16 + (lane >> 4) * 4 + j;
                const float val = v[j] + bp[o];
                float2 vv = make_float2(val, val);
                size_t base = (size_t)o * NF + pbase;
                *(float2*)&out[base] = vv;
                *(float2*)&out[base + WFULL] = vv;
            }
        }
    }
}

extern "C" void kernel_launch(void* const* d_in, const int* in_sizes, int n_in,
                              void* d_out, int out_size, void* d_ws, size_t ws_size,
                              hipStream_t stream) {
    (void)in_sizes; (void)n_in; (void)out_size; (void)ws_size;
    const float* x    = (const float*)d_in[0];
    const float* wq   = (const float*)d_in[1];
    const float* bq   = (const float*)d_in[2];
    const float* wd   = (const float*)d_in[3];
    const float* bd   = (const float*)d_in[4];
    const float* wp   = (const float*)d_in[5];
    const float* bp   = (const float*)d_in[6];
    const float* temp = (const float*)d_in[7];
    const float* a1   = (const float*)d_in[8];
    const float* a2   = (const float*)d_in[9];
    const float* a3   = (const float*)d_in[10];
    const float* a4   = (const float*)d_in[11];
    float* out = (float*)d_out;
    float* ws  = (float*)d_ws;

    // persistent region (44.4 MB high-water, proven R3-R7):
    float* pooled = ws;                       // 10,616,832 floats (42.5 MB)
    float* Wc     = ws + 10616832;            // 18,432
    ushort* wh    = (ushort*)(Wc + 18432 + 19200);  // 884,736 bf16 total
    ushort* wl    = wh + 442368;

    // carved out of pooled once pooled is dead (after dwconv):
    ushort* o96h   = (ushort*)ws;                              // 3,538,944 bf16
    ushort* o96l   = o96h + 3538944;                           // 3,538,944 bf16
    float*  Spart  = (float*)((char*)ws + 14155776);           // 884,736 f32
    float*  qnpart = Spart + 884736;                           // 18,432 f32
    float*  knpart = qnpart + 18432;                           // 18,432 f32
    ushort* wph    = (ushort*)(knpart + 18432);                // 147,456 bf16
    ushort* wpl    = wph + 147456;                             // 147,456 bf16

    float* qkvdw = out;                       // q,k,v after dw conv staged in d_out
    ushort* xh = (ushort*)d_out;              // x hi staged in d_out (dead pre-dwconv)
    ushort* xl = xh + 14155776;

    hipLaunchKernelGGL(k_prep,      dim3(3456),    dim3(256), 0, stream, wq, wh, wl, x, xh, xl);
    hipLaunchKernelGGL(k_qkv_mfma,  dim3(1296),    dim3(256), 0, stream, xh, xl, wh, wl, bq, pooled, 0);
    hipLaunchKernelGGL(k_qkv_mfma,  dim3(1296),    dim3(256), 0, stream, xh, xl, wh, wl, bq, pooled, 144);
    hipLaunchKernelGGL(k_dwconv,    dim3(10368),   dim3(256), 0, stream, pooled, wd, bd, qkvdw);
    hipLaunchKernelGGL(k_prep_w,    dim3(576),     dim3(256), 0, stream, wp, wph, wpl, D * D);
    hipLaunchKernelGGL(k_attn_part, dim3(48, 8),   dim3(256), 0, stream, qkvdw, Spart, qnpart, knpart);
    hipLaunchKernelGGL(k_softmax,   dim3(96),      dim3(256), 0, stream, Spart, qnpart, knpart, temp, a1, a2, a3, a4, Wc);
    hipLaunchKernelGGL(k_av_gelu,   dim3(864),     dim3(256), 0, stream, qkvdw, Wc, o96h, o96l);
    hipLaunchKernelGGL(k_proj_mfma, dim3(216),     dim3(256), 0, stream, wph, wpl, o96h, o96l, bp, out);
}

// Round 10
// 231.017 us; speedup vs baseline: 1.7052x; 1.7052x over previous
//
#include <hip/hip_runtime.h>
#include <hip/hip_bf16.h>
#include <math.h>

#define NH    8
#define CPH   48
#define D     384
#define QC    1152
#define HF    192
#define WFULL 192
#define HP    96
#define WP    96
#define NP    9216    // 96*96
#define NF    36864   // 192*192

typedef __attribute__((ext_vector_type(8))) short short8;
typedef __attribute__((ext_vector_type(4))) float f32x4;

__device__ __forceinline__ float gelu_exact(float v) {
    return 0.5f * v * (1.f + erff(v * 0.70710678118654752440f));
}
__device__ __forceinline__ ushort f2bf(float v) {
    __hip_bfloat16 h = __float2bfloat16(v);
    return *reinterpret_cast<ushort*>(&h);
}
__device__ __forceinline__ float bf2f(ushort u) {
    __hip_bfloat16 h = *reinterpret_cast<__hip_bfloat16*>(&u);
    return __bfloat162float(h);
}

// ---------------- P1: split fp32 -> bf16 hi/lo (wp; runs AFTER dwconv -------
// because its destination lives in the then-dead pooled region) --------------
__global__ __launch_bounds__(256) void k_prep_w(
    const float* __restrict__ w, ushort* __restrict__ wh, ushort* __restrict__ wl, int n) {
    int i = blockIdx.x * 256 + threadIdx.x;
    if (i < n) {
        float v = w[i];
        ushort h = f2bf(v);
        wh[i] = h;
        wl[i] = f2bf(v - bf2f(h));
    }
}

// ---------------- P2 (fused): wq split + x split/transpose -------------------
// blocks [0,1728): wq -> wh/wl.  blocks [1728,3456): x -> xh/xl in
// n' = (py*96+px)*4 + (y&1)*2 + (x&1) pool-quad-contiguous pixel order.
__global__ __launch_bounds__(256) void k_prep(
    const float* __restrict__ wq, ushort* __restrict__ wh, ushort* __restrict__ wl,
    const float* __restrict__ x, ushort* __restrict__ xh, ushort* __restrict__ xl) {
    __shared__ float xf[64][128];   // 32 KB (unused by w-branch)
    const int tid = threadIdx.x;
    if (blockIdx.x < 1728) {
        int i = blockIdx.x * 256 + tid;          // 442368 = 1728*256 exact
        float v = wq[i];
        ushort h = f2bf(v);
        wh[i] = h;
        wl[i] = f2bf(v - bf2f(h));
        return;
    }
    const int e  = blockIdx.x - 1728;
    const int xt = e % 288, kt = e / 288;
    const int kk = kt * 64;
    const int q0 = xt * 32;                  // 32 pool quads (one pool row chunk)
    const int py = q0 / 96, px0 = q0 - py * 96;
    const int y0 = 2 * py, xcol0 = 2 * px0;
    const float* xb = x + (size_t)kk * NF + (size_t)y0 * WFULL + xcol0;
#pragma unroll
    for (int it = 0; it < 8; it++) {
        int li = tid + 256 * it;
        int ch = li >> 5, r = (li >> 4) & 1, c4 = (li & 15) * 4;
        float4 v = *(const float4*)&xb[(size_t)ch * NF + r * WFULL + c4];
        *(float4*)&xf[ch][r * 64 + c4] = v;
    }
    __syncthreads();
    const int row = tid >> 1, half = tid & 1;
    const int r = (row >> 1) & 1;
    const int col = (row >> 2) * 2 + (row & 1);
    const int src = r * 64 + col;
    const size_t np = (size_t)xt * 128 + row;
    ushort hbuf[32], lbuf[32];
#pragma unroll
    for (int j = 0; j < 32; j++) {
        float v = xf[half * 32 + j][src];
        ushort h = f2bf(v);
        hbuf[j] = h;
        lbuf[j] = f2bf(v - bf2f(h));
    }
    ushort* dh = xh + np * D + kk + half * 32;
    ushort* dl = xl + np * D + kk + half * 32;
#pragma unroll
    for (int j = 0; j < 4; j++) {
        *(short8*)&dh[j * 8] = *(const short8*)&hbuf[j * 8];
        *(short8*)&dl[j * 8] = *(const short8*)&lbuf[j * 8];
    }
}

// ---------------- K1: qkv 1x1 conv as bf16x3 MFMA GEMM + fused 2x2 maxpool ---
// Split into two half-M launches (mbase = 0 / 144) for per-kernel visibility.
__global__ __launch_bounds__(256) void k_qkv_mfma(
    const ushort* __restrict__ xh, const ushort* __restrict__ xl,
    const ushort* __restrict__ wh, const ushort* __restrict__ wl,
    const float* __restrict__ bq, float* __restrict__ pooled, int mbase) {
    __shared__ ushort lds[2][4][4096];  // [buf][Ah,Al,Bh,Bl][128 rows x 32 bf16]
    const int tid = threadIdx.x;
    const int lane = tid & 63, wid = tid >> 6;
    const int wm = wid >> 1, wn = wid & 1;

    const int d   = blockIdx.x;        // 0..1295, HW XCD = d % 8
    const int xcd = d & 7;
    const int idx = d >> 3;            // 0..161
    const int by  = mbase + xcd * 18 + idx / 9;
    const int bx  = idx % 9;
    const int n0 = bx * 128;
    const int m0 = by * 128;

    const ushort* srcs[4];
    srcs[0] = xh + (size_t)m0 * D;
    srcs[1] = xl + (size_t)m0 * D;
    srcs[2] = wh + (size_t)n0 * D;
    srcs[3] = wl + (size_t)n0 * D;

    f32x4 acc[4][4];
#pragma unroll
    for (int i = 0; i < 4; i++)
#pragma unroll
        for (int j = 0; j < 4; j++) acc[i][j] = (f32x4){0.f, 0.f, 0.f, 0.f};

    int a_off[4], b_off[4];
#pragma unroll
    for (int f = 0; f < 4; f++) {
        int ra = wm * 64 + f * 16 + (lane & 15);
        a_off[f] = ra * 64 + ((((lane >> 4) ^ ((ra >> 1) & 3)) & 3) << 4);
        int rb = wn * 64 + f * 16 + (lane & 15);
        b_off[f] = rb * 64 + ((((lane >> 4) ^ ((rb >> 1) & 3)) & 3) << 4);
    }

    auto STAGE = [&](int buf, int kk) {
#pragma unroll
        for (int i = 0; i < 8; i++) {
            const int mat = i >> 1;
            const int cm  = ((i & 1) << 2) | wid;
            const int row = cm * 16 + (lane >> 2);
            const int scol = (((lane & 3) ^ ((row >> 1) & 3)) & 3) << 4;
            const ushort* src = srcs[mat] + (size_t)row * D + kk + (scol >> 1);
            __builtin_amdgcn_global_load_lds(
                (const __attribute__((address_space(1))) void*)src,
                (__attribute__((address_space(3))) void*)&lds[buf][mat][cm * 512],
                16, 0, 0);
        }
    };

    STAGE(0, 0);
    for (int t = 0; t < 12; ++t) {
        const int cur = t & 1;
        if (t < 11) {
            STAGE(cur ^ 1, (t + 1) * 32);
            asm volatile("s_waitcnt vmcnt(8)" ::: "memory");
        } else {
            asm volatile("s_waitcnt vmcnt(0)" ::: "memory");
        }
        __builtin_amdgcn_s_barrier();

        const char* bA0 = (const char*)&lds[cur][0][0];
        const char* bA1 = (const char*)&lds[cur][1][0];
        const char* bB0 = (const char*)&lds[cur][2][0];
        const char* bB1 = (const char*)&lds[cur][3][0];
        short8 A[2][4], B[2][4];
#pragma unroll
        for (int f = 0; f < 4; f++) {
            A[0][f] = *(const short8*)(bA0 + a_off[f]);
            A[1][f] = *(const short8*)(bA1 + a_off[f]);
            B[0][f] = *(const short8*)(bB0 + b_off[f]);
            B[1][f] = *(const short8*)(bB1 + b_off[f]);
        }
        __builtin_amdgcn_s_setprio(1);
#pragma unroll
        for (int fm = 0; fm < 4; fm++)
#pragma unroll
            for (int fn = 0; fn < 4; fn++) {
                acc[fm][fn] = __builtin_amdgcn_mfma_f32_16x16x32_bf16(A[0][fm], B[0][fn], acc[fm][fn], 0, 0, 0);
                acc[fm][fn] = __builtin_amdgcn_mfma_f32_16x16x32_bf16(A[0][fm], B[1][fn], acc[fm][fn], 0, 0, 0);
                acc[fm][fn] = __builtin_amdgcn_mfma_f32_16x16x32_bf16(A[1][fm], B[0][fn], acc[fm][fn], 0, 0, 0);
            }
        __builtin_amdgcn_s_setprio(0);
        asm volatile("s_waitcnt lgkmcnt(0)" ::: "memory");
        __builtin_amdgcn_s_barrier();
    }

    const int p_base = by * 32 + wm * 16 + (lane >> 4);
#pragma unroll
    for (int fn = 0; fn < 4; fn++) {
        const int o = n0 + wn * 64 + fn * 16 + (lane & 15);
        const float b = bq[o];
#pragma unroll
        for (int fm = 0; fm < 4; fm++) {
            f32x4 v = acc[fm][fn];
            float mx = fmaxf(fmaxf(v.x, v.y), fmaxf(v.z, v.w)) + b;
            pooled[(size_t)o * NP + p_base + fm * 4] = mx;
        }
    }
}

// ---------------- K2: depthwise 3x3 conv, vectorized 4 outputs/thread --------
__global__ __launch_bounds__(256) void k_dwconv(
    const float* __restrict__ pooled, const float* __restrict__ wd,
    const float* __restrict__ bd, float* __restrict__ out) {
    int gid = blockIdx.x * 256 + threadIdx.x;   // 0 .. 2,654,207
    int xq = gid % 24, t = gid / 24;
    int y = t % 96, ch = t / 96;                // ch uniform per block (2304/ch)
    const float* src = pooled + (size_t)ch * NP;
    const float* w = wd + ch * 9;
    const int x0 = xq * 4;
    float b = bd[ch];
    float o0 = b, o1 = b, o2 = b, o3 = b;
#pragma unroll
    for (int dy = 0; dy < 3; dy++) {
        int yy = y + dy - 1;
        if (yy < 0 || yy >= HP) continue;
        const float* r = src + yy * WP;
        float4 c = *(const float4*)&r[x0];
        float lm = (x0 > 0) ? r[x0 - 1] : 0.f;
        float rm = (x0 < 92) ? r[x0 + 4] : 0.f;
        float w0 = w[dy * 3], w1 = w[dy * 3 + 1], w2 = w[dy * 3 + 2];
        o0 += w0 * lm  + w1 * c.x + w2 * c.y;
        o1 += w0 * c.x + w1 * c.y + w2 * c.z;
        o2 += w0 * c.y + w1 * c.z + w2 * c.w;
        o3 += w0 * c.z + w1 * c.w + w2 * rm;
    }
    *(float4*)&out[(size_t)ch * NP + y * WP + x0] = make_float4(o0, o1, o2, o3);
}

// ---------------- K3a: attn partials, no atomics -----------------------------
__global__ __launch_bounds__(256) void k_attn_part(
    const float* __restrict__ qkv, float* __restrict__ Spart,
    float* __restrict__ qnpart, float* __restrict__ knpart) {
    __shared__ float qs[48][196], ks[48][196];
    const int tid = threadIdx.x;
    const int p = blockIdx.x, h = blockIdx.y;
    const int n0 = p * 192;
    const float* qb = qkv + (size_t)(h * CPH) * NP + n0;
    const float* kb = qkv + (size_t)(D + h * CPH) * NP + n0;
#pragma unroll
    for (int it = 0; it < 9; it++) {
        int li = tid + 256 * it;             // 0..2303 float4s
        int row = li / 48, c4 = (li - row * 48) * 4;
        *(float4*)&qs[row][c4] = *(const float4*)&qb[(size_t)row * NP + c4];
        *(float4*)&ks[row][c4] = *(const float4*)&kb[(size_t)row * NP + c4];
    }
    __syncthreads();
    const int tr = (tid >> 4) * 3, tc = (tid & 15) * 3;
    float acc[3][3] = {};
    for (int n = 0; n < 192; n++) {
        float qv[3], kv[3];
#pragma unroll
        for (int i = 0; i < 3; i++) qv[i] = qs[tr + i][n];
#pragma unroll
        for (int j = 0; j < 3; j++) kv[j] = ks[tc + j][n];
#pragma unroll
        for (int i = 0; i < 3; i++)
#pragma unroll
            for (int j = 0; j < 3; j++) acc[i][j] += qv[i] * kv[j];
    }
    float* Sp = Spart + (size_t)(p * NH + h) * 2304;
#pragma unroll
    for (int i = 0; i < 3; i++)
#pragma unroll
        for (int j = 0; j < 3; j++)
            Sp[(tr + i) * CPH + tc + j] = acc[i][j];
    if (tid < 48) {
        float s = 0.f;
        for (int n = 0; n < 192; n++) s += qs[tid][n] * qs[tid][n];
        qnpart[(p * NH + h) * CPH + tid] = s;
    } else if (tid >= 64 && tid < 112) {
        int t2 = tid - 64;
        float s = 0.f;
        for (int n = 0; n < 192; n++) s += ks[t2][n] * ks[t2][n];
        knpart[(p * NH + h) * CPH + t2] = s;
    }
}

// ---------------- K4 (fused red+softmax): partials -> Wc ---------------------
__global__ __launch_bounds__(256) void k_softmax(
    const float* __restrict__ Spart, const float* __restrict__ qnpart,
    const float* __restrict__ knpart, const float* __restrict__ temp,
    const float* __restrict__ a1, const float* __restrict__ a2,
    const float* __restrict__ a3, const float* __restrict__ a4,
    float* __restrict__ Wc) {
    __shared__ float rowbuf[4][64];
    int lane = threadIdx.x & 63;
    int w = threadIdx.x >> 6;
    int row = blockIdx.x * 4 + w;
    int h = row / CPH, c = row % CPH;
    float a = -INFINITY;
    if (lane < CPH) {
        float s = 0.f, q2 = 0.f, k2 = 0.f;
        for (int p = 0; p < 48; p++) {
            int base = (p * NH + h);
            s  += Spart[(size_t)base * 2304 + c * CPH + lane];
            q2 += qnpart[base * CPH + c];
            k2 += knpart[base * CPH + lane];
        }
        float nq = fmaxf(sqrtf(fmaxf(q2, 0.f)), 1e-12f);
        float nk = fmaxf(sqrtf(fmaxf(k2, 0.f)), 1e-12f);
        a = s / (nq * nk) * temp[h];
    }
    rowbuf[w][lane] = a;
    __syncthreads();
    int rank = 0;
    float m = -INFINITY;
    for (int j = 0; j < CPH; j++) {
        float vj = rowbuf[w][j];
        m = fmaxf(m, vj);
        rank += (vj > a || (vj == a && j < lane)) ? 1 : 0;
    }
    float e = (lane < CPH) ? expf(a - m) : 0.f;
    float4 p;
    p.x = (rank < 24) ? e : 0.f;
    p.y = (rank < 32) ? e : 0.f;
    p.z = (rank < 36) ? e : 0.f;
    p.w = (rank < 38) ? e : 0.f;
#pragma unroll
    for (int off = 32; off > 0; off >>= 1) {
        p.x += __shfl_xor(p.x, off);
        p.y += __shfl_xor(p.y, off);
        p.z += __shfl_xor(p.z, off);
        p.w += __shfl_xor(p.w, off);
    }
    if (lane < CPH) {
        float wv = 0.f;
        if (rank < 24) wv += a1[0] / p.x;
        if (rank < 32) wv += a2[0] / p.y;
        if (rank < 36) wv += a3[0] / p.z;
        if (rank < 38) wv += a4[0] / p.w;
        Wc[(h * CPH + c) * CPH + lane] = e * wv;
    }
}

// ---------------- K5: gelu(Wc @ v) -> bf16 hi/lo rows [n][384] ---------------
// R10: v staged in LDS (48x256, coalesced float4), compute loop unroll-4 only
// -> no global loads in loop, no spill (R9 had 256 VGPR + 500 MB scratch).
__global__ __launch_bounds__(256) void k_av_gelu(
    const float* __restrict__ qkv, const float* __restrict__ Wc,
    ushort* __restrict__ o96h, ushort* __restrict__ o96l) {
    __shared__ float Ws[48][16];    // 3 KB W^T slice for this (head, third)
    __shared__ float vs[48][256];   // 48 KB v slice (48 d x 256 px)
    const int tid = threadIdx.x;
    const int b = blockIdx.x;          // h(8) x third(3) x chunk(36)
    const int h = b / 108;
    const int rem = b - h * 108;
    const int t3 = rem / 36;
    const int pc = rem - t3 * 36;
    const int c0 = t3 * 16;
    const int px0 = pc * 256;
    for (int li = tid; li < 768; li += 256) {
        int dd = li >> 4, cc = li & 15;
        Ws[dd][cc] = Wc[(h * CPH + c0 + cc) * CPH + dd];
    }
    const float* vb = qkv + (size_t)(2 * D + h * CPH) * NP + px0;
#pragma unroll
    for (int it = 0; it < 12; it++) {
        int li = tid + 256 * it;          // 0..3071 float4 slots
        int dd = li >> 6, c4 = (li & 63) * 4;
        *(float4*)&vs[dd][c4] = *(const float4*)&vb[(size_t)dd * NP + c4];
    }
    __syncthreads();
    float acc[16] = {};
#pragma unroll 4
    for (int dd = 0; dd < 48; dd++) {
        float vv = vs[dd][tid];
        float4 w0 = *(const float4*)&Ws[dd][0];
        float4 w1 = *(const float4*)&Ws[dd][4];
        float4 w2 = *(const float4*)&Ws[dd][8];
        float4 w3 = *(const float4*)&Ws[dd][12];
        acc[0]  += w0.x * vv; acc[1]  += w0.y * vv; acc[2]  += w0.z * vv; acc[3]  += w0.w * vv;
        acc[4]  += w1.x * vv; acc[5]  += w1.y * vv; acc[6]  += w1.z * vv; acc[7]  += w1.w * vv;
        acc[8]  += w2.x * vv; acc[9]  += w2.y * vv; acc[10] += w2.z * vv; acc[11] += w2.w * vv;
        acc[12] += w3.x * vv; acc[13] += w3.y * vv; acc[14] += w3.z * vv; acc[15] += w3.w * vv;
    }
    short8 hv0, hv1, lv0, lv1;
#pragma unroll
    for (int j = 0; j < 8; j++) {
        float g = gelu_exact(acc[j]);
        ushort hu = f2bf(g);
        hv0[j] = (short)hu; lv0[j] = (short)f2bf(g - bf2f(hu));
        float g2 = gelu_exact(acc[8 + j]);
        ushort hu2 = f2bf(g2);
        hv1[j] = (short)hu2; lv1[j] = (short)f2bf(g2 - bf2f(hu2));
    }
    size_t base = (size_t)(px0 + tid) * D + h * CPH + c0;
    *(short8*)&o96h[base] = hv0;
    *(short8*)&o96h[base + 8] = hv1;
    *(short8*)&o96l[base] = lv0;
    *(short8*)&o96l[base + 8] = lv1;
}

// ---------------- K6: proj 1x1 as bf16x3 MFMA + nearest 2x upsample ----------
__global__ __launch_bounds__(256) void k_proj_mfma(
    const ushort* __restrict__ wph, const ushort* __restrict__ wpl,
    const ushort* __restrict__ o96h, const ushort* __restrict__ o96l,
    const float* __restrict__ bp, float* __restrict__ out) {
    __shared__ ushort lds[2][4][4096];
    const int tid = threadIdx.x;
    const int lane = tid & 63, wid = tid >> 6;
    const int wm = wid >> 1, wn = wid & 1;

    const int d   = blockIdx.x;        // 0..215
    const int xcd = d & 7;
    const int idx = d >> 3;            // 0..26
    const int nt  = xcd * 9 + idx / 3; // n-tile 0..71
    const int ot  = idx % 3;           // o-tile 0..2
    const int o0 = ot * 128;
    const int n0 = nt * 128;

    const ushort* srcs[4];
    srcs[0] = wph + (size_t)o0 * D;
    srcs[1] = wpl + (size_t)o0 * D;
    srcs[2] = o96h + (size_t)n0 * D;
    srcs[3] = o96l + (size_t)n0 * D;

    f32x4 acc[4][4];
#pragma unroll
    for (int i = 0; i < 4; i++)
#pragma unroll
        for (int j = 0; j < 4; j++) acc[i][j] = (f32x4){0.f, 0.f, 0.f, 0.f};

    int a_off[4], b_off[4];
#pragma unroll
    for (int f = 0; f < 4; f++) {
        int ra = wm * 64 + f * 16 + (lane & 15);
        a_off[f] = ra * 64 + ((((lane >> 4) ^ ((ra >> 1) & 3)) & 3) << 4);
        int rb = wn * 64 + f * 16 + (lane & 15);
        b_off[f] = rb * 64 + ((((lane >> 4) ^ ((rb >> 1) & 3)) & 3) << 4);
    }

    auto STAGE = [&](int buf, int kk) {
#pragma unroll
        for (int i = 0; i < 8; i++) {
            const int mat = i >> 1;
            const int cm  = ((i & 1) << 2) | wid;
            const int row = cm * 16 + (lane >> 2);
            const int scol = (((lane & 3) ^ ((row >> 1) & 3)) & 3) << 4;
            const ushort* src = srcs[mat] + (size_t)row * D + kk + (scol >> 1);
            __builtin_amdgcn_global_load_lds(
                (const __attribute__((address_space(1))) void*)src,
                (__attribute__((address_space(3))) void*)&lds[buf][mat][cm * 512],
                16, 0, 0);
        }
    };

    STAGE(0, 0);
    for (int t = 0; t < 12; ++t) {
        const int cur = t & 1;
        if (t < 11) {
            STAGE(cur ^ 1, (t + 1) * 32);
            asm volatile("s_waitcnt vmcnt(8)" ::: "memory");
        } else {
            asm volatile("s_waitcnt vmcnt(0)" ::: "memory");
        }
        __builtin_amdgcn_s_barrier();

        const char* bA0 = (const char*)&lds[cur][0][0];
        const char* bA1 = (const char*)&lds[cur][1][0];
        const char* bB0 = (const char*)&lds[cur][2][0];
        const char* bB1 = (const char*)&lds[cur][3][0];
        short8 A[2][4], B[2][4];
#pragma unroll
        for (int f = 0; f < 4; f++) {
            A[0][f] = *(const short8*)(bA0 + a_off[f]);
            A[1][f] = *(const short8*)(bA1 + a_off[f]);
            B[0][f] = *(const short8*)(bB0 + b_off[f]);
            B[1][f] = *(const short8*)(bB1 + b_off[f]);
        }
        __builtin_amdgcn_s_setprio(1);
#pragma unroll
        for (int fm = 0; fm < 4; fm++)
#pragma unroll
            for (int fn = 0; fn < 4; fn++) {
                acc[fm][fn] = __builtin_amdgcn_mfma_f32_16x16x32_bf16(A[0][fm], B[0][fn], acc[fm][fn], 0, 0, 0);
                acc[fm][fn] = __builtin_amdgcn_mfma_f32_16x16x32_bf16(A[0][fm], B[1][fn], acc[fm][fn], 0, 0, 0);
                acc[fm][fn] = __builtin_amdgcn_mfma_f32_16x16x32_bf16(A[1][fm], B[0][fn], acc[fm][fn], 0, 0, 0);
            }
        __builtin_amdgcn_s_setprio(0);
        asm volatile("s_waitcnt lgkmcnt(0)" ::: "memory");
        __builtin_amdgcn_s_barrier();
    }

#pragma unroll
    for (int fn = 0; fn < 4; fn++) {
        const int n = n0 + wn * 64 + fn * 16 + (lane & 15);
        const int y = n / WP, xcol = n - y * WP;
        const size_t pbase = (size_t)(2 * y) * WFULL + 2 * xcol;
#pragma unroll
        for (int fm = 0; fm < 4; fm++) {
            f32x4 v = acc[fm][fn];
#pragma unroll
            for (int j = 0; j < 4; j++) {
                const int o = o0 + wm * 64 + fm * 16 + (lane >> 4) * 4 + j;
                const float val = v[j] + bp[o];
                float2 vv = make_float2(val, val);
                size_t base = (size_t)o * NF + pbase;
                *(float2*)&out[base] = vv;
                *(float2*)&out[base + WFULL] = vv;
            }
        }
    }
}

extern "C" void kernel_launch(void* const* d_in, const int* in_sizes, int n_in,
                              void* d_out, int out_size, void* d_ws, size_t ws_size,
                              hipStream_t stream) {
    (void)in_sizes; (void)n_in; (void)out_size; (void)ws_size;
    const float* x    = (const float*)d_in[0];
    const float* wq   = (const float*)d_in[1];
    const float* bq   = (const float*)d_in[2];
    const float* wd   = (const float*)d_in[3];
    const float* bd   = (const float*)d_in[4];
    const float* wp   = (const float*)d_in[5];
    const float* bp   = (const float*)d_in[6];
    const float* temp = (const float*)d_in[7];
    const float* a1   = (const float*)d_in[8];
    const float* a2   = (const float*)d_in[9];
    const float* a3   = (const float*)d_in[10];
    const float* a4   = (const float*)d_in[11];
    float* out = (float*)d_out;
    float* ws  = (float*)d_ws;

    // persistent region (44.4 MB high-water, proven R3-R9):
    float* pooled = ws;                       // 10,616,832 floats (42.5 MB)
    float* Wc     = ws + 10616832;            // 18,432
    ushort* wh    = (ushort*)(Wc + 18432 + 19200);  // 884,736 bf16 total
    ushort* wl    = wh + 442368;

    // carved out of pooled once pooled is dead (after dwconv):
    ushort* o96h   = (ushort*)ws;                              // 3,538,944 bf16
    ushort* o96l   = o96h + 3538944;                           // 3,538,944 bf16
    float*  Spart  = (float*)((char*)ws + 14155776);           // 884,736 f32
    float*  qnpart = Spart + 884736;                           // 18,432 f32
    float*  knpart = qnpart + 18432;                           // 18,432 f32
    ushort* wph    = (ushort*)(knpart + 18432);                // 147,456 bf16
    ushort* wpl    = wph + 147456;                             // 147,456 bf16

    float* qkvdw = out;                       // q,k,v after dw conv staged in d_out
    ushort* xh = (ushort*)d_out;              // x hi staged in d_out (dead pre-dwconv)
    ushort* xl = xh + 14155776;

    hipLaunchKernelGGL(k_prep,      dim3(3456),    dim3(256), 0, stream, wq, wh, wl, x, xh, xl);
    hipLaunchKernelGGL(k_qkv_mfma,  dim3(1296),    dim3(256), 0, stream, xh, xl, wh, wl, bq, pooled, 0);
    hipLaunchKernelGGL(k_qkv_mfma,  dim3(1296),    dim3(256), 0, stream, xh, xl, wh, wl, bq, pooled, 144);
    hipLaunchKernelGGL(k_dwconv,    dim3(10368),   dim3(256), 0, stream, pooled, wd, bd, qkvdw);
    hipLaunchKernelGGL(k_prep_w,    dim3(576),     dim3(256), 0, stream, wp, wph, wpl, D * D);
    hipLaunchKernelGGL(k_attn_part, dim3(48, 8),   dim3(256), 0, stream, qkvdw, Spart, qnpart, knpart);
    hipLaunchKernelGGL(k_softmax,   dim3(96),      dim3(256), 0, stream, Spart, qnpart, knpart, temp, a1, a2, a3, a4, Wc);
    hipLaunchKernelGGL(k_av_gelu,   dim3(864),     dim3(256), 0, stream, qkvdw, Wc, o96h, o96l);
    hipLaunchKernelGGL(k_proj_mfma, dim3(216),     dim3(256), 0, stream, wph, wpl, o96h, o96l, bp, out);
}

// Round 11
// 218.268 us; speedup vs baseline: 1.8048x; 1.0584x over previous
//
#include <hip/hip_runtime.h>
#include <hip/hip_bf16.h>
#include <math.h>

#define NH    8
#define CPH   48
#define D     384
#define QC    1152
#define HF    192
#define WFULL 192
#define HP    96
#define WP    96
#define NP    9216    // 96*96
#define NF    36864   // 192*192

typedef __attribute__((ext_vector_type(8))) short short8;
typedef __attribute__((ext_vector_type(4))) float f32x4;

__device__ __forceinline__ float gelu_exact(float v) {
    return 0.5f * v * (1.f + erff(v * 0.70710678118654752440f));
}
__device__ __forceinline__ ushort f2bf(float v) {
    __hip_bfloat16 h = __float2bfloat16(v);
    return *reinterpret_cast<ushort*>(&h);
}
__device__ __forceinline__ float bf2f(ushort u) {
    __hip_bfloat16 h = *reinterpret_cast<__hip_bfloat16*>(&u);
    return __bfloat162float(h);
}

// ---------------- P1: split fp32 -> bf16 hi/lo (wp; runs AFTER dwconv -------
// because its destination lives in the then-dead pooled region) --------------
__global__ __launch_bounds__(256) void k_prep_w(
    const float* __restrict__ w, ushort* __restrict__ wh, ushort* __restrict__ wl, int n) {
    int i = blockIdx.x * 256 + threadIdx.x;
    if (i < n) {
        float v = w[i];
        ushort h = f2bf(v);
        wh[i] = h;
        wl[i] = f2bf(v - bf2f(h));
    }
}

// ---------------- P2 (fused): wq split + x split/transpose -------------------
// blocks [0,1728): wq -> wh/wl.  blocks [1728,3456): x -> xh/xl in
// n' = (py*96+px)*4 + (y&1)*2 + (x&1) pool-quad-contiguous pixel order.
__global__ __launch_bounds__(256) void k_prep(
    const float* __restrict__ wq, ushort* __restrict__ wh, ushort* __restrict__ wl,
    const float* __restrict__ x, ushort* __restrict__ xh, ushort* __restrict__ xl) {
    __shared__ float xf[64][128];   // 32 KB (unused by w-branch)
    const int tid = threadIdx.x;
    if (blockIdx.x < 1728) {
        int i = blockIdx.x * 256 + tid;          // 442368 = 1728*256 exact
        float v = wq[i];
        ushort h = f2bf(v);
        wh[i] = h;
        wl[i] = f2bf(v - bf2f(h));
        return;
    }
    const int e  = blockIdx.x - 1728;
    const int xt = e % 288, kt = e / 288;
    const int kk = kt * 64;
    const int q0 = xt * 32;                  // 32 pool quads (one pool row chunk)
    const int py = q0 / 96, px0 = q0 - py * 96;
    const int y0 = 2 * py, xcol0 = 2 * px0;
    const float* xb = x + (size_t)kk * NF + (size_t)y0 * WFULL + xcol0;
#pragma unroll
    for (int it = 0; it < 8; it++) {
        int li = tid + 256 * it;
        int ch = li >> 5, r = (li >> 4) & 1, c4 = (li & 15) * 4;
        float4 v = *(const float4*)&xb[(size_t)ch * NF + r * WFULL + c4];
        *(float4*)&xf[ch][r * 64 + c4] = v;
    }
    __syncthreads();
    const int row = tid >> 1, half = tid & 1;
    const int r = (row >> 1) & 1;
    const int col = (row >> 2) * 2 + (row & 1);
    const int src = r * 64 + col;
    const size_t np = (size_t)xt * 128 + row;
    ushort hbuf[32], lbuf[32];
#pragma unroll
    for (int j = 0; j < 32; j++) {
        float v = xf[half * 32 + j][src];
        ushort h = f2bf(v);
        hbuf[j] = h;
        lbuf[j] = f2bf(v - bf2f(h));
    }
    ushort* dh = xh + np * D + kk + half * 32;
    ushort* dl = xl + np * D + kk + half * 32;
#pragma unroll
    for (int j = 0; j < 4; j++) {
        *(short8*)&dh[j * 8] = *(const short8*)&hbuf[j * 8];
        *(short8*)&dl[j * 8] = *(const short8*)&lbuf[j * 8];
    }
}

// ---------------- K1: qkv 1x1 conv as bf16x3 MFMA GEMM + fused 2x2 maxpool ---
// R11: merged single launch, 512 threads / 8 waves per 128x128 tile
// (wave sub-tile 64x32, acc 4x2) -> 16 waves/CU for stall hiding.
__global__ __launch_bounds__(512) void k_qkv_mfma(
    const ushort* __restrict__ xh, const ushort* __restrict__ xl,
    const ushort* __restrict__ wh, const ushort* __restrict__ wl,
    const float* __restrict__ bq, float* __restrict__ pooled) {
    __shared__ ushort lds[2][4][4096];  // [buf][Ah,Al,Bh,Bl][128 rows x 32 bf16]
    const int tid = threadIdx.x;
    const int lane = tid & 63, wid = tid >> 6;   // 8 waves
    const int wm = wid >> 2, wn = wid & 3;       // 2 x 4 wave grid

    const int d   = blockIdx.x;        // 0..2591, HW XCD = d % 8
    const int xcd = d & 7;
    const int idx = d >> 3;            // 0..323
    const int by  = xcd * 36 + idx / 9;
    const int bx  = idx % 9;
    const int n0 = bx * 128;
    const int m0 = by * 128;

    const ushort* srcs[4];
    srcs[0] = xh + (size_t)m0 * D;
    srcs[1] = xl + (size_t)m0 * D;
    srcs[2] = wh + (size_t)n0 * D;
    srcs[3] = wl + (size_t)n0 * D;

    f32x4 acc[4][2];
#pragma unroll
    for (int i = 0; i < 4; i++)
#pragma unroll
        for (int j = 0; j < 2; j++) acc[i][j] = (f32x4){0.f, 0.f, 0.f, 0.f};

    // fragment ds_read byte offsets within one 8KB tile, 2-bit chunk XOR swizzle
    int a_off[4], b_off[2];
#pragma unroll
    for (int f = 0; f < 4; f++) {
        int ra = wm * 64 + f * 16 + (lane & 15);
        a_off[f] = ra * 64 + ((((lane >> 4) ^ ((ra >> 1) & 3)) & 3) << 4);
    }
#pragma unroll
    for (int f = 0; f < 2; f++) {
        int rb = wn * 32 + f * 16 + (lane & 15);
        b_off[f] = rb * 64 + ((((lane >> 4) ^ ((rb >> 1) & 3)) & 3) << 4);
    }

    // stage one 32KB K-step tile: 8 waves x 4 issues x 64 lanes x 16B.
    // issue i: matrix i, chunk = wid (1KB each); linear LDS dest,
    // inverse-swizzled global source (both-sides rule).
    auto STAGE = [&](int buf, int kk) {
#pragma unroll
        for (int i = 0; i < 4; i++) {
            const int row = wid * 16 + (lane >> 2);
            const int scol = (((lane & 3) ^ ((row >> 1) & 3)) & 3) << 4;
            const ushort* src = srcs[i] + (size_t)row * D + kk + (scol >> 1);
            __builtin_amdgcn_global_load_lds(
                (const __attribute__((address_space(1))) void*)src,
                (__attribute__((address_space(3))) void*)&lds[buf][i][wid * 512],
                16, 0, 0);
        }
    };

    STAGE(0, 0);
    for (int t = 0; t < 12; ++t) {
        const int cur = t & 1;
        if (t < 11) {
            STAGE(cur ^ 1, (t + 1) * 32);
            asm volatile("s_waitcnt vmcnt(4)" ::: "memory");  // tile t landed
        } else {
            asm volatile("s_waitcnt vmcnt(0)" ::: "memory");
        }
        __builtin_amdgcn_s_barrier();

        const char* bA0 = (const char*)&lds[cur][0][0];
        const char* bA1 = (const char*)&lds[cur][1][0];
        const char* bB0 = (const char*)&lds[cur][2][0];
        const char* bB1 = (const char*)&lds[cur][3][0];
        short8 A[2][4], B[2][2];
#pragma unroll
        for (int f = 0; f < 4; f++) {
            A[0][f] = *(const short8*)(bA0 + a_off[f]);
            A[1][f] = *(const short8*)(bA1 + a_off[f]);
        }
#pragma unroll
        for (int f = 0; f < 2; f++) {
            B[0][f] = *(const short8*)(bB0 + b_off[f]);
            B[1][f] = *(const short8*)(bB1 + b_off[f]);
        }
        __builtin_amdgcn_s_setprio(1);
#pragma unroll
        for (int fm = 0; fm < 4; fm++)
#pragma unroll
            for (int fn = 0; fn < 2; fn++) {
                acc[fm][fn] = __builtin_amdgcn_mfma_f32_16x16x32_bf16(A[0][fm], B[0][fn], acc[fm][fn], 0, 0, 0);
                acc[fm][fn] = __builtin_amdgcn_mfma_f32_16x16x32_bf16(A[0][fm], B[1][fn], acc[fm][fn], 0, 0, 0);
                acc[fm][fn] = __builtin_amdgcn_mfma_f32_16x16x32_bf16(A[1][fm], B[0][fn], acc[fm][fn], 0, 0, 0);
            }
        __builtin_amdgcn_s_setprio(0);
        asm volatile("s_waitcnt lgkmcnt(0)" ::: "memory");
        __builtin_amdgcn_s_barrier();
    }

    // epilogue: 4 C-regs of each fragment = one pool quad (n' quad-contiguous)
    const int p_base = by * 32 + wm * 16 + (lane >> 4);
#pragma unroll
    for (int fn = 0; fn < 2; fn++) {
        const int o = n0 + wn * 32 + fn * 16 + (lane & 15);
        const float b = bq[o];
#pragma unroll
        for (int fm = 0; fm < 4; fm++) {
            f32x4 v = acc[fm][fn];
            float mx = fmaxf(fmaxf(v.x, v.y), fmaxf(v.z, v.w)) + b;
            pooled[(size_t)o * NP + p_base + fm * 4] = mx;
        }
    }
}

// ---------------- K2: depthwise 3x3 conv, vectorized 4 outputs/thread --------
__global__ __launch_bounds__(256) void k_dwconv(
    const float* __restrict__ pooled, const float* __restrict__ wd,
    const float* __restrict__ bd, float* __restrict__ out) {
    int gid = blockIdx.x * 256 + threadIdx.x;   // 0 .. 2,654,207
    int xq = gid % 24, t = gid / 24;
    int y = t % 96, ch = t / 96;                // ch uniform per block (2304/ch)
    const float* src = pooled + (size_t)ch * NP;
    const float* w = wd + ch * 9;
    const int x0 = xq * 4;
    float b = bd[ch];
    float o0 = b, o1 = b, o2 = b, o3 = b;
#pragma unroll
    for (int dy = 0; dy < 3; dy++) {
        int yy = y + dy - 1;
        if (yy < 0 || yy >= HP) continue;
        const float* r = src + yy * WP;
        float4 c = *(const float4*)&r[x0];
        float lm = (x0 > 0) ? r[x0 - 1] : 0.f;
        float rm = (x0 < 92) ? r[x0 + 4] : 0.f;
        float w0 = w[dy * 3], w1 = w[dy * 3 + 1], w2 = w[dy * 3 + 2];
        o0 += w0 * lm  + w1 * c.x + w2 * c.y;
        o1 += w0 * c.x + w1 * c.y + w2 * c.z;
        o2 += w0 * c.y + w1 * c.z + w2 * c.w;
        o3 += w0 * c.z + w1 * c.w + w2 * rm;
    }
    *(float4*)&out[(size_t)ch * NP + y * WP + x0] = make_float4(o0, o1, o2, o3);
}

// ---------------- K3a: attn partials, no atomics -----------------------------
__global__ __launch_bounds__(256) void k_attn_part(
    const float* __restrict__ qkv, float* __restrict__ Spart,
    float* __restrict__ qnpart, float* __restrict__ knpart) {
    __shared__ float qs[48][196], ks[48][196];
    const int tid = threadIdx.x;
    const int p = blockIdx.x, h = blockIdx.y;
    const int n0 = p * 192;
    const float* qb = qkv + (size_t)(h * CPH) * NP + n0;
    const float* kb = qkv + (size_t)(D + h * CPH) * NP + n0;
#pragma unroll
    for (int it = 0; it < 9; it++) {
        int li = tid + 256 * it;             // 0..2303 float4s
        int row = li / 48, c4 = (li - row * 48) * 4;
        *(float4*)&qs[row][c4] = *(const float4*)&qb[(size_t)row * NP + c4];
        *(float4*)&ks[row][c4] = *(const float4*)&kb[(size_t)row * NP + c4];
    }
    __syncthreads();
    const int tr = (tid >> 4) * 3, tc = (tid & 15) * 3;
    float acc[3][3] = {};
    for (int n = 0; n < 192; n++) {
        float qv[3], kv[3];
#pragma unroll
        for (int i = 0; i < 3; i++) qv[i] = qs[tr + i][n];
#pragma unroll
        for (int j = 0; j < 3; j++) kv[j] = ks[tc + j][n];
#pragma unroll
        for (int i = 0; i < 3; i++)
#pragma unroll
            for (int j = 0; j < 3; j++) acc[i][j] += qv[i] * kv[j];
    }
    float* Sp = Spart + (size_t)(p * NH + h) * 2304;
#pragma unroll
    for (int i = 0; i < 3; i++)
#pragma unroll
        for (int j = 0; j < 3; j++)
            Sp[(tr + i) * CPH + tc + j] = acc[i][j];
    if (tid < 48) {
        float s = 0.f;
        for (int n = 0; n < 192; n++) s += qs[tid][n] * qs[tid][n];
        qnpart[(p * NH + h) * CPH + tid] = s;
    } else if (tid >= 64 && tid < 112) {
        int t2 = tid - 64;
        float s = 0.f;
        for (int n = 0; n < 192; n++) s += ks[t2][n] * ks[t2][n];
        knpart[(p * NH + h) * CPH + t2] = s;
    }
}

// ---------------- K4 (fused red+softmax): partials -> Wc ---------------------
__global__ __launch_bounds__(256) void k_softmax(
    const float* __restrict__ Spart, const float* __restrict__ qnpart,
    const float* __restrict__ knpart, const float* __restrict__ temp,
    const float* __restrict__ a1, const float* __restrict__ a2,
    const float* __restrict__ a3, const float* __restrict__ a4,
    float* __restrict__ Wc) {
    __shared__ float rowbuf[4][64];
    int lane = threadIdx.x & 63;
    int w = threadIdx.x >> 6;
    int row = blockIdx.x * 4 + w;
    int h = row / CPH, c = row % CPH;
    float a = -INFINITY;
    if (lane < CPH) {
        float s = 0.f, q2 = 0.f, k2 = 0.f;
        for (int p = 0; p < 48; p++) {
            int base = (p * NH + h);
            s  += Spart[(size_t)base * 2304 + c * CPH + lane];
            q2 += qnpart[base * CPH + c];
            k2 += knpart[base * CPH + lane];
        }
        float nq = fmaxf(sqrtf(fmaxf(q2, 0.f)), 1e-12f);
        float nk = fmaxf(sqrtf(fmaxf(k2, 0.f)), 1e-12f);
        a = s / (nq * nk) * temp[h];
    }
    rowbuf[w][lane] = a;
    __syncthreads();
    int rank = 0;
    float m = -INFINITY;
    for (int j = 0; j < CPH; j++) {
        float vj = rowbuf[w][j];
        m = fmaxf(m, vj);
        rank += (vj > a || (vj == a && j < lane)) ? 1 : 0;
    }
    float e = (lane < CPH) ? expf(a - m) : 0.f;
    float4 p;
    p.x = (rank < 24) ? e : 0.f;
    p.y = (rank < 32) ? e : 0.f;
    p.z = (rank < 36) ? e : 0.f;
    p.w = (rank < 38) ? e : 0.f;
#pragma unroll
    for (int off = 32; off > 0; off >>= 1) {
        p.x += __shfl_xor(p.x, off);
        p.y += __shfl_xor(p.y, off);
        p.z += __shfl_xor(p.z, off);
        p.w += __shfl_xor(p.w, off);
    }
    if (lane < CPH) {
        float wv = 0.f;
        if (rank < 24) wv += a1[0] / p.x;
        if (rank < 32) wv += a2[0] / p.y;
        if (rank < 36) wv += a3[0] / p.z;
        if (rank < 38) wv += a4[0] / p.w;
        Wc[(h * CPH + c) * CPH + lane] = e * wv;
    }
}

// ---------------- K5: gelu(Wc @ v) -> bf16 hi/lo rows [n][384] ---------------
// v staged in LDS (48x256, coalesced float4), compute loop unroll-4 only.
__global__ __launch_bounds__(256) void k_av_gelu(
    const float* __restrict__ qkv, const float* __restrict__ Wc,
    ushort* __restrict__ o96h, ushort* __restrict__ o96l) {
    __shared__ float Ws[48][16];    // 3 KB W^T slice for this (head, third)
    __shared__ float vs[48][256];   // 48 KB v slice (48 d x 256 px)
    const int tid = threadIdx.x;
    const int b = blockIdx.x;          // h(8) x third(3) x chunk(36)
    const int h = b / 108;
    const int rem = b - h * 108;
    const int t3 = rem / 36;
    const int pc = rem - t3 * 36;
    const int c0 = t3 * 16;
    const int px0 = pc * 256;
    for (int li = tid; li < 768; li += 256) {
        int dd = li >> 4, cc = li & 15;
        Ws[dd][cc] = Wc[(h * CPH + c0 + cc) * CPH + dd];
    }
    const float* vb = qkv + (size_t)(2 * D + h * CPH) * NP + px0;
#pragma unroll
    for (int it = 0; it < 12; it++) {
        int li = tid + 256 * it;          // 0..3071 float4 slots
        int dd = li >> 6, c4 = (li & 63) * 4;
        *(float4*)&vs[dd][c4] = *(const float4*)&vb[(size_t)dd * NP + c4];
    }
    __syncthreads();
    float acc[16] = {};
#pragma unroll 4
    for (int dd = 0; dd < 48; dd++) {
        float vv = vs[dd][tid];
        float4 w0 = *(const float4*)&Ws[dd][0];
        float4 w1 = *(const float4*)&Ws[dd][4];
        float4 w2 = *(const float4*)&Ws[dd][8];
        float4 w3 = *(const float4*)&Ws[dd][12];
        acc[0]  += w0.x * vv; acc[1]  += w0.y * vv; acc[2]  += w0.z * vv; acc[3]  += w0.w * vv;
        acc[4]  += w1.x * vv; acc[5]  += w1.y * vv; acc[6]  += w1.z * vv; acc[7]  += w1.w * vv;
        acc[8]  += w2.x * vv; acc[9]  += w2.y * vv; acc[10] += w2.z * vv; acc[11] += w2.w * vv;
        acc[12] += w3.x * vv; acc[13] += w3.y * vv; acc[14] += w3.z * vv; acc[15] += w3.w * vv;
    }
    short8 hv0, hv1, lv0, lv1;
#pragma unroll
    for (int j = 0; j < 8; j++) {
        float g = gelu_exact(acc[j]);
        ushort hu = f2bf(g);
        hv0[j] = (short)hu; lv0[j] = (short)f2bf(g - bf2f(hu));
        float g2 = gelu_exact(acc[8 + j]);
        ushort hu2 = f2bf(g2);
        hv1[j] = (short)hu2; lv1[j] = (short)f2bf(g2 - bf2f(hu2));
    }
    size_t base = (size_t)(px0 + tid) * D + h * CPH + c0;
    *(short8*)&o96h[base] = hv0;
    *(short8*)&o96h[base + 8] = hv1;
    *(short8*)&o96l[base] = lv0;
    *(short8*)&o96l[base + 8] = lv1;
}

// ---------------- K6: proj 1x1 as bf16x3 MFMA + nearest 2x upsample ----------
__global__ __launch_bounds__(256) void k_proj_mfma(
    const ushort* __restrict__ wph, const ushort* __restrict__ wpl,
    const ushort* __restrict__ o96h, const ushort* __restrict__ o96l,
    const float* __restrict__ bp, float* __restrict__ out) {
    __shared__ ushort lds[2][4][4096];
    const int tid = threadIdx.x;
    const int lane = tid & 63, wid = tid >> 6;
    const int wm = wid >> 1, wn = wid & 1;

    const int d   = blockIdx.x;        // 0..215
    const int xcd = d & 7;
    const int idx = d >> 3;            // 0..26
    const int nt  = xcd * 9 + idx / 3; // n-tile 0..71
    const int ot  = idx % 3;           // o-tile 0..2
    const int o0 = ot * 128;
    const int n0 = nt * 128;

    const ushort* srcs[4];
    srcs[0] = wph + (size_t)o0 * D;
    srcs[1] = wpl + (size_t)o0 * D;
    srcs[2] = o96h + (size_t)n0 * D;
    srcs[3] = o96l + (size_t)n0 * D;

    f32x4 acc[4][4];
#pragma unroll
    for (int i = 0; i < 4; i++)
#pragma unroll
        for (int j = 0; j < 4; j++) acc[i][j] = (f32x4){0.f, 0.f, 0.f, 0.f};

    int a_off[4], b_off[4];
#pragma unroll
    for (int f = 0; f < 4; f++) {
        int ra = wm * 64 + f * 16 + (lane & 15);
        a_off[f] = ra * 64 + ((((lane >> 4) ^ ((ra >> 1) & 3)) & 3) << 4);
        int rb = wn * 64 + f * 16 + (lane & 15);
        b_off[f] = rb * 64 + ((((lane >> 4) ^ ((rb >> 1) & 3)) & 3) << 4);
    }

    auto STAGE = [&](int buf, int kk) {
#pragma unroll
        for (int i = 0; i < 8; i++) {
            const int mat = i >> 1;
            const int cm  = ((i & 1) << 2) | wid;
            const int row = cm * 16 + (lane >> 2);
            const int scol = (((lane & 3) ^ ((row >> 1) & 3)) & 3) << 4;
            const ushort* src = srcs[mat] + (size_t)row * D + kk + (scol >> 1);
            __builtin_amdgcn_global_load_lds(
                (const __attribute__((address_space(1))) void*)src,
                (__attribute__((address_space(3))) void*)&lds[buf][mat][cm * 512],
                16, 0, 0);
        }
    };

    STAGE(0, 0);
    for (int t = 0; t < 12; ++t) {
        const int cur = t & 1;
        if (t < 11) {
            STAGE(cur ^ 1, (t + 1) * 32);
            asm volatile("s_waitcnt vmcnt(8)" ::: "memory");
        } else {
            asm volatile("s_waitcnt vmcnt(0)" ::: "memory");
        }
        __builtin_amdgcn_s_barrier();

        const char* bA0 = (const char*)&lds[cur][0][0];
        const char* bA1 = (const char*)&lds[cur][1][0];
        const char* bB0 = (const char*)&lds[cur][2][0];
        const char* bB1 = (const char*)&lds[cur][3][0];
        short8 A[2][4], B[2][4];
#pragma unroll
        for (int f = 0; f < 4; f++) {
            A[0][f] = *(const short8*)(bA0 + a_off[f]);
            A[1][f] = *(const short8*)(bA1 + a_off[f]);
            B[0][f] = *(const short8*)(bB0 + b_off[f]);
            B[1][f] = *(const short8*)(bB1 + b_off[f]);
        }
        __builtin_amdgcn_s_setprio(1);
#pragma unroll
        for (int fm = 0; fm < 4; fm++)
#pragma unroll
            for (int fn = 0; fn < 4; fn++) {
                acc[fm][fn] = __builtin_amdgcn_mfma_f32_16x16x32_bf16(A[0][fm], B[0][fn], acc[fm][fn], 0, 0, 0);
                acc[fm][fn] = __builtin_amdgcn_mfma_f32_16x16x32_bf16(A[0][fm], B[1][fn], acc[fm][fn], 0, 0, 0);
                acc[fm][fn] = __builtin_amdgcn_mfma_f32_16x16x32_bf16(A[1][fm], B[0][fn], acc[fm][fn], 0, 0, 0);
            }
        __builtin_amdgcn_s_setprio(0);
        asm volatile("s_waitcnt lgkmcnt(0)" ::: "memory");
        __builtin_amdgcn_s_barrier();
    }

#pragma unroll
    for (int fn = 0; fn < 4; fn++) {
        const int n = n0 + wn * 64 + fn * 16 + (lane & 15);
        const int y = n / WP, xcol = n - y * WP;
        const size_t pbase = (size_t)(2 * y) * WFULL + 2 * xcol;
#pragma unroll
        for (int fm = 0; fm < 4; fm++) {
            f32x4 v = acc[fm][fn];
#pragma unroll
            for (int j = 0; j < 4; j++) {
                const int o = o0 + wm * 64 + fm * 16 + (lane >> 4) * 4 + j;
                const float val = v[j] + bp[o];
                float2 vv = make_float2(val, val);
                size_t base = (size_t)o * NF + pbase;
                *(float2*)&out[base] = vv;
                *(float2*)&out[base + WFULL] = vv;
            }
        }
    }
}

extern "C" void kernel_launch(void* const* d_in, const int* in_sizes, int n_in,
                              void* d_out, int out_size, void* d_ws, size_t ws_size,
                              hipStream_t stream) {
    (void)in_sizes; (void)n_in; (void)out_size; (void)ws_size;
    const float* x    = (const float*)d_in[0];
    const float* wq   = (const float*)d_in[1];
    const float* bq   = (const float*)d_in[2];
    const float* wd   = (const float*)d_in[3];
    const float* bd   = (const float*)d_in[4];
    const float* wp   = (const float*)d_in[5];
    const float* bp   = (const float*)d_in[6];
    const float* temp = (const float*)d_in[7];
    const float* a1   = (const float*)d_in[8];
    const float* a2   = (const float*)d_in[9];
    const float* a3   = (const float*)d_in[10];
    const float* a4   = (const float*)d_in[11];
    float* out = (float*)d_out;
    float* ws  = (float*)d_ws;

    // persistent region (44.4 MB high-water, proven R3-R10):
    float* pooled = ws;                       // 10,616,832 floats (42.5 MB)
    float* Wc     = ws + 10616832;            // 18,432
    ushort* wh    = (ushort*)(Wc + 18432 + 19200);  // 884,736 bf16 total
    ushort* wl    = wh + 442368;

    // carved out of pooled once pooled is dead (after dwconv):
    ushort* o96h   = (ushort*)ws;                              // 3,538,944 bf16
    ushort* o96l   = o96h + 3538944;                           // 3,538,944 bf16
    float*  Spart  = (float*)((char*)ws + 14155776);           // 884,736 f32
    float*  qnpart = Spart + 884736;                           // 18,432 f32
    float*  knpart = qnpart + 18432;                           // 18,432 f32
    ushort* wph    = (ushort*)(knpart + 18432);                // 147,456 bf16
    ushort* wpl    = wph + 147456;                             // 147,456 bf16

    float* qkvdw = out;                       // q,k,v after dw conv staged in d_out
    ushort* xh = (ushort*)d_out;              // x hi staged in d_out (dead pre-dwconv)
    ushort* xl = xh + 14155776;

    hipLaunchKernelGGL(k_prep,      dim3(3456),    dim3(256), 0, stream, wq, wh, wl, x, xh, xl);
    hipLaunchKernelGGL(k_qkv_mfma,  dim3(2592),    dim3(512), 0, stream, xh, xl, wh, wl, bq, pooled);
    hipLaunchKernelGGL(k_dwconv,    dim3(10368),   dim3(256), 0, stream, pooled, wd, bd, qkvdw);
    hipLaunchKernelGGL(k_prep_w,    dim3(576),     dim3(256), 0, stream, wp, wph, wpl, D * D);
    hipLaunchKernelGGL(k_attn_part, dim3(48, 8),   dim3(256), 0, stream, qkvdw, Spart, qnpart, knpart);
    hipLaunchKernelGGL(k_softmax,   dim3(96),      dim3(256), 0, stream, Spart, qnpart, knpart, temp, a1, a2, a3, a4, Wc);
    hipLaunchKernelGGL(k_av_gelu,   dim3(864),     dim3(256), 0, stream, qkvdw, Wc, o96h, o96l);
    hipLaunchKernelGGL(k_proj_mfma, dim3(216),     dim3(256), 0, stream, wph, wpl, o96h, o96l, bp, out);
}

// Round 12
// 215.086 us; speedup vs baseline: 1.8315x; 1.0148x over previous
//
#include <hip/hip_runtime.h>
#include <hip/hip_bf16.h>
#include <math.h>

#define NH    8
#define CPH   48
#define D     384
#define QC    1152
#define HF    192
#define WFULL 192
#define HP    96
#define WP    96
#define NP    9216    // 96*96
#define NF    36864   // 192*192

typedef __attribute__((ext_vector_type(8))) short short8;
typedef __attribute__((ext_vector_type(4))) float f32x4;

__device__ __forceinline__ float gelu_exact(float v) {
    return 0.5f * v * (1.f + erff(v * 0.70710678118654752440f));
}
__device__ __forceinline__ ushort f2bf(float v) {
    __hip_bfloat16 h = __float2bfloat16(v);
    return *reinterpret_cast<ushort*>(&h);
}
__device__ __forceinline__ float bf2f(ushort u) {
    __hip_bfloat16 h = *reinterpret_cast<__hip_bfloat16*>(&u);
    return __bfloat162float(h);
}

// ---------------- P1: split fp32 -> bf16 hi/lo (wp; runs AFTER dwconv -------
// because its destination lives in the then-dead pooled region) --------------
__global__ __launch_bounds__(256) void k_prep_w(
    const float* __restrict__ w, ushort* __restrict__ wh, ushort* __restrict__ wl, int n) {
    int i = blockIdx.x * 256 + threadIdx.x;
    if (i < n) {
        float v = w[i];
        ushort h = f2bf(v);
        wh[i] = h;
        wl[i] = f2bf(v - bf2f(h));
    }
}

// ---------------- P2 (fused): wq split + x split/transpose -------------------
// blocks [0,1728): wq -> wh/wl.  blocks [1728,3456): x -> xh/xl in
// n' = (py*96+px)*4 + (y&1)*2 + (x&1) pool-quad-contiguous pixel order.
__global__ __launch_bounds__(256) void k_prep(
    const float* __restrict__ wq, ushort* __restrict__ wh, ushort* __restrict__ wl,
    const float* __restrict__ x, ushort* __restrict__ xh, ushort* __restrict__ xl) {
    __shared__ float xf[64][128];   // 32 KB (unused by w-branch)
    const int tid = threadIdx.x;
    if (blockIdx.x < 1728) {
        int i = blockIdx.x * 256 + tid;          // 442368 = 1728*256 exact
        float v = wq[i];
        ushort h = f2bf(v);
        wh[i] = h;
        wl[i] = f2bf(v - bf2f(h));
        return;
    }
    const int e  = blockIdx.x - 1728;
    const int xt = e % 288, kt = e / 288;
    const int kk = kt * 64;
    const int q0 = xt * 32;                  // 32 pool quads (one pool row chunk)
    const int py = q0 / 96, px0 = q0 - py * 96;
    const int y0 = 2 * py, xcol0 = 2 * px0;
    const float* xb = x + (size_t)kk * NF + (size_t)y0 * WFULL + xcol0;
#pragma unroll
    for (int it = 0; it < 8; it++) {
        int li = tid + 256 * it;
        int ch = li >> 5, r = (li >> 4) & 1, c4 = (li & 15) * 4;
        float4 v = *(const float4*)&xb[(size_t)ch * NF + r * WFULL + c4];
        *(float4*)&xf[ch][r * 64 + c4] = v;
    }
    __syncthreads();
    const int row = tid >> 1, half = tid & 1;
    const int r = (row >> 1) & 1;
    const int col = (row >> 2) * 2 + (row & 1);
    const int src = r * 64 + col;
    const size_t np = (size_t)xt * 128 + row;
    ushort hbuf[32], lbuf[32];
#pragma unroll
    for (int j = 0; j < 32; j++) {
        float v = xf[half * 32 + j][src];
        ushort h = f2bf(v);
        hbuf[j] = h;
        lbuf[j] = f2bf(v - bf2f(h));
    }
    ushort* dh = xh + np * D + kk + half * 32;
    ushort* dl = xl + np * D + kk + half * 32;
#pragma unroll
    for (int j = 0; j < 4; j++) {
        *(short8*)&dh[j * 8] = *(const short8*)&hbuf[j * 8];
        *(short8*)&dl[j * 8] = *(const short8*)&lbuf[j * 8];
    }
}

// ---------------- K1: qkv 1x1 conv as bf16x3 MFMA GEMM + fused 2x2 maxpool ---
// R12: ONE barrier per K-step.  Body = {vmcnt(0 own loads) -> barrier ->
// STAGE(next) -> ds_read(cur) -> MFMA}.  Safe because a wave reaches the
// iter-t barrier only after its iter-(t-1) MFMAs consumed buf[(t-1)&1],
// and STAGE(t+1 -> that buffer) is issued after the barrier.
__global__ __launch_bounds__(512) void k_qkv_mfma(
    const ushort* __restrict__ xh, const ushort* __restrict__ xl,
    const ushort* __restrict__ wh, const ushort* __restrict__ wl,
    const float* __restrict__ bq, float* __restrict__ pooled) {
    __shared__ ushort lds[2][4][4096];  // [buf][Ah,Al,Bh,Bl][128 rows x 32 bf16]
    const int tid = threadIdx.x;
    const int lane = tid & 63, wid = tid >> 6;   // 8 waves
    const int wm = wid >> 2, wn = wid & 3;       // 2 x 4 wave grid

    const int d   = blockIdx.x;        // 0..2591, HW XCD = d % 8
    const int xcd = d & 7;
    const int idx = d >> 3;            // 0..323
    const int by  = xcd * 36 + idx / 9;
    const int bx  = idx % 9;
    const int n0 = bx * 128;
    const int m0 = by * 128;

    const ushort* srcs[4];
    srcs[0] = xh + (size_t)m0 * D;
    srcs[1] = xl + (size_t)m0 * D;
    srcs[2] = wh + (size_t)n0 * D;
    srcs[3] = wl + (size_t)n0 * D;

    f32x4 acc[4][2];
#pragma unroll
    for (int i = 0; i < 4; i++)
#pragma unroll
        for (int j = 0; j < 2; j++) acc[i][j] = (f32x4){0.f, 0.f, 0.f, 0.f};

    // fragment ds_read byte offsets within one 8KB tile, 2-bit chunk XOR swizzle
    int a_off[4], b_off[2];
#pragma unroll
    for (int f = 0; f < 4; f++) {
        int ra = wm * 64 + f * 16 + (lane & 15);
        a_off[f] = ra * 64 + ((((lane >> 4) ^ ((ra >> 1) & 3)) & 3) << 4);
    }
#pragma unroll
    for (int f = 0; f < 2; f++) {
        int rb = wn * 32 + f * 16 + (lane & 15);
        b_off[f] = rb * 64 + ((((lane >> 4) ^ ((rb >> 1) & 3)) & 3) << 4);
    }

    // stage one 32KB K-step tile: 8 waves x 4 issues x 64 lanes x 16B.
    auto STAGE = [&](int buf, int kk) {
#pragma unroll
        for (int i = 0; i < 4; i++) {
            const int row = wid * 16 + (lane >> 2);
            const int scol = (((lane & 3) ^ ((row >> 1) & 3)) & 3) << 4;
            const ushort* src = srcs[i] + (size_t)row * D + kk + (scol >> 1);
            __builtin_amdgcn_global_load_lds(
                (const __attribute__((address_space(1))) void*)src,
                (__attribute__((address_space(3))) void*)&lds[buf][i][wid * 512],
                16, 0, 0);
        }
    };

    STAGE(0, 0);
    for (int t = 0; t < 12; ++t) {
        const int cur = t & 1;
        // own 4 loads of tile t are the only outstanding VMEM ops
        asm volatile("s_waitcnt vmcnt(0)" ::: "memory");
        __builtin_amdgcn_s_barrier();
        if (t < 11) STAGE(cur ^ 1, (t + 1) * 32);

        const char* bA0 = (const char*)&lds[cur][0][0];
        const char* bA1 = (const char*)&lds[cur][1][0];
        const char* bB0 = (const char*)&lds[cur][2][0];
        const char* bB1 = (const char*)&lds[cur][3][0];
        short8 A[2][4], B[2][2];
#pragma unroll
        for (int f = 0; f < 4; f++) {
            A[0][f] = *(const short8*)(bA0 + a_off[f]);
            A[1][f] = *(const short8*)(bA1 + a_off[f]);
        }
#pragma unroll
        for (int f = 0; f < 2; f++) {
            B[0][f] = *(const short8*)(bB0 + b_off[f]);
            B[1][f] = *(const short8*)(bB1 + b_off[f]);
        }
        __builtin_amdgcn_s_setprio(1);
#pragma unroll
        for (int fm = 0; fm < 4; fm++)
#pragma unroll
            for (int fn = 0; fn < 2; fn++) {
                acc[fm][fn] = __builtin_amdgcn_mfma_f32_16x16x32_bf16(A[0][fm], B[0][fn], acc[fm][fn], 0, 0, 0);
                acc[fm][fn] = __builtin_amdgcn_mfma_f32_16x16x32_bf16(A[0][fm], B[1][fn], acc[fm][fn], 0, 0, 0);
                acc[fm][fn] = __builtin_amdgcn_mfma_f32_16x16x32_bf16(A[1][fm], B[0][fn], acc[fm][fn], 0, 0, 0);
            }
        __builtin_amdgcn_s_setprio(0);
    }

    // epilogue: 4 C-regs of each fragment = one pool quad (n' quad-contiguous)
    const int p_base = by * 32 + wm * 16 + (lane >> 4);
#pragma unroll
    for (int fn = 0; fn < 2; fn++) {
        const int o = n0 + wn * 32 + fn * 16 + (lane & 15);
        const float b = bq[o];
#pragma unroll
        for (int fm = 0; fm < 4; fm++) {
            f32x4 v = acc[fm][fn];
            float mx = fmaxf(fmaxf(v.x, v.y), fmaxf(v.z, v.w)) + b;
            pooled[(size_t)o * NP + p_base + fm * 4] = mx;
        }
    }
}

// ---------------- K2: depthwise 3x3 conv, vectorized 4 outputs/thread --------
__global__ __launch_bounds__(256) void k_dwconv(
    const float* __restrict__ pooled, const float* __restrict__ wd,
    const float* __restrict__ bd, float* __restrict__ out) {
    int gid = blockIdx.x * 256 + threadIdx.x;   // 0 .. 2,654,207
    int xq = gid % 24, t = gid / 24;
    int y = t % 96, ch = t / 96;                // ch uniform per block (2304/ch)
    const float* src = pooled + (size_t)ch * NP;
    const float* w = wd + ch * 9;
    const int x0 = xq * 4;
    float b = bd[ch];
    float o0 = b, o1 = b, o2 = b, o3 = b;
#pragma unroll
    for (int dy = 0; dy < 3; dy++) {
        int yy = y + dy - 1;
        if (yy < 0 || yy >= HP) continue;
        const float* r = src + yy * WP;
        float4 c = *(const float4*)&r[x0];
        float lm = (x0 > 0) ? r[x0 - 1] : 0.f;
        float rm = (x0 < 92) ? r[x0 + 4] : 0.f;
        float w0 = w[dy * 3], w1 = w[dy * 3 + 1], w2 = w[dy * 3 + 2];
        o0 += w0 * lm  + w1 * c.x + w2 * c.y;
        o1 += w0 * c.x + w1 * c.y + w2 * c.z;
        o2 += w0 * c.y + w1 * c.z + w2 * c.w;
        o3 += w0 * c.z + w1 * c.w + w2 * rm;
    }
    *(float4*)&out[(size_t)ch * NP + y * WP + x0] = make_float4(o0, o1, o2, o3);
}

// ---------------- K3a: attn partials, no atomics -----------------------------
__global__ __launch_bounds__(256) void k_attn_part(
    const float* __restrict__ qkv, float* __restrict__ Spart,
    float* __restrict__ qnpart, float* __restrict__ knpart) {
    __shared__ float qs[48][196], ks[48][196];
    const int tid = threadIdx.x;
    const int p = blockIdx.x, h = blockIdx.y;
    const int n0 = p * 192;
    const float* qb = qkv + (size_t)(h * CPH) * NP + n0;
    const float* kb = qkv + (size_t)(D + h * CPH) * NP + n0;
#pragma unroll
    for (int it = 0; it < 9; it++) {
        int li = tid + 256 * it;             // 0..2303 float4s
        int row = li / 48, c4 = (li - row * 48) * 4;
        *(float4*)&qs[row][c4] = *(const float4*)&qb[(size_t)row * NP + c4];
        *(float4*)&ks[row][c4] = *(const float4*)&kb[(size_t)row * NP + c4];
    }
    __syncthreads();
    const int tr = (tid >> 4) * 3, tc = (tid & 15) * 3;
    float acc[3][3] = {};
    for (int n = 0; n < 192; n++) {
        float qv[3], kv[3];
#pragma unroll
        for (int i = 0; i < 3; i++) qv[i] = qs[tr + i][n];
#pragma unroll
        for (int j = 0; j < 3; j++) kv[j] = ks[tc + j][n];
#pragma unroll
        for (int i = 0; i < 3; i++)
#pragma unroll
            for (int j = 0; j < 3; j++) acc[i][j] += qv[i] * kv[j];
    }
    float* Sp = Spart + (size_t)(p * NH + h) * 2304;
#pragma unroll
    for (int i = 0; i < 3; i++)
#pragma unroll
        for (int j = 0; j < 3; j++)
            Sp[(tr + i) * CPH + tc + j] = acc[i][j];
    if (tid < 48) {
        float s = 0.f;
        for (int n = 0; n < 192; n++) s += qs[tid][n] * qs[tid][n];
        qnpart[(p * NH + h) * CPH + tid] = s;
    } else if (tid >= 64 && tid < 112) {
        int t2 = tid - 64;
        float s = 0.f;
        for (int n = 0; n < 192; n++) s += ks[t2][n] * ks[t2][n];
        knpart[(p * NH + h) * CPH + t2] = s;
    }
}

// ---------------- K4 (fused red+softmax): partials -> Wc ---------------------
__global__ __launch_bounds__(256) void k_softmax(
    const float* __restrict__ Spart, const float* __restrict__ qnpart,
    const float* __restrict__ knpart, const float* __restrict__ temp,
    const float* __restrict__ a1, const float* __restrict__ a2,
    const float* __restrict__ a3, const float* __restrict__ a4,
    float* __restrict__ Wc) {
    __shared__ float rowbuf[4][64];
    int lane = threadIdx.x & 63;
    int w = threadIdx.x >> 6;
    int row = blockIdx.x * 4 + w;
    int h = row / CPH, c = row % CPH;
    float a = -INFINITY;
    if (lane < CPH) {
        float s = 0.f, q2 = 0.f, k2 = 0.f;
        for (int p = 0; p < 48; p++) {
            int base = (p * NH + h);
            s  += Spart[(size_t)base * 2304 + c * CPH + lane];
            q2 += qnpart[base * CPH + c];
            k2 += knpart[base * CPH + lane];
        }
        float nq = fmaxf(sqrtf(fmaxf(q2, 0.f)), 1e-12f);
        float nk = fmaxf(sqrtf(fmaxf(k2, 0.f)), 1e-12f);
        a = s / (nq * nk) * temp[h];
    }
    rowbuf[w][lane] = a;
    __syncthreads();
    int rank = 0;
    float m = -INFINITY;
    for (int j = 0; j < CPH; j++) {
        float vj = rowbuf[w][j];
        m = fmaxf(m, vj);
        rank += (vj > a || (vj == a && j < lane)) ? 1 : 0;
    }
    float e = (lane < CPH) ? expf(a - m) : 0.f;
    float4 p;
    p.x = (rank < 24) ? e : 0.f;
    p.y = (rank < 32) ? e : 0.f;
    p.z = (rank < 36) ? e : 0.f;
    p.w = (rank < 38) ? e : 0.f;
#pragma unroll
    for (int off = 32; off > 0; off >>= 1) {
        p.x += __shfl_xor(p.x, off);
        p.y += __shfl_xor(p.y, off);
        p.z += __shfl_xor(p.z, off);
        p.w += __shfl_xor(p.w, off);
    }
    if (lane < CPH) {
        float wv = 0.f;
        if (rank < 24) wv += a1[0] / p.x;
        if (rank < 32) wv += a2[0] / p.y;
        if (rank < 36) wv += a3[0] / p.z;
        if (rank < 38) wv += a4[0] / p.w;
        Wc[(h * CPH + c) * CPH + lane] = e * wv;
    }
}

// ---------------- K5: gelu(Wc @ v) -> bf16 hi/lo rows [n][384] ---------------
// v staged in LDS (48x256, coalesced float4), compute loop unroll-4 only.
__global__ __launch_bounds__(256) void k_av_gelu(
    const float* __restrict__ qkv, const float* __restrict__ Wc,
    ushort* __restrict__ o96h, ushort* __restrict__ o96l) {
    __shared__ float Ws[48][16];    // 3 KB W^T slice for this (head, third)
    __shared__ float vs[48][256];   // 48 KB v slice (48 d x 256 px)
    const int tid = threadIdx.x;
    const int b = blockIdx.x;          // h(8) x third(3) x chunk(36)
    const int h = b / 108;
    const int rem = b - h * 108;
    const int t3 = rem / 36;
    const int pc = rem - t3 * 36;
    const int c0 = t3 * 16;
    const int px0 = pc * 256;
    for (int li = tid; li < 768; li += 256) {
        int dd = li >> 4, cc = li & 15;
        Ws[dd][cc] = Wc[(h * CPH + c0 + cc) * CPH + dd];
    }
    const float* vb = qkv + (size_t)(2 * D + h * CPH) * NP + px0;
#pragma unroll
    for (int it = 0; it < 12; it++) {
        int li = tid + 256 * it;          // 0..3071 float4 slots
        int dd = li >> 6, c4 = (li & 63) * 4;
        *(float4*)&vs[dd][c4] = *(const float4*)&vb[(size_t)dd * NP + c4];
    }
    __syncthreads();
    float acc[16] = {};
#pragma unroll 4
    for (int dd = 0; dd < 48; dd++) {
        float vv = vs[dd][tid];
        float4 w0 = *(const float4*)&Ws[dd][0];
        float4 w1 = *(const float4*)&Ws[dd][4];
        float4 w2 = *(const float4*)&Ws[dd][8];
        float4 w3 = *(const float4*)&Ws[dd][12];
        acc[0]  += w0.x * vv; acc[1]  += w0.y * vv; acc[2]  += w0.z * vv; acc[3]  += w0.w * vv;
        acc[4]  += w1.x * vv; acc[5]  += w1.y * vv; acc[6]  += w1.z * vv; acc[7]  += w1.w * vv;
        acc[8]  += w2.x * vv; acc[9]  += w2.y * vv; acc[10] += w2.z * vv; acc[11] += w2.w * vv;
        acc[12] += w3.x * vv; acc[13] += w3.y * vv; acc[14] += w3.z * vv; acc[15] += w3.w * vv;
    }
    short8 hv0, hv1, lv0, lv1;
#pragma unroll
    for (int j = 0; j < 8; j++) {
        float g = gelu_exact(acc[j]);
        ushort hu = f2bf(g);
        hv0[j] = (short)hu; lv0[j] = (short)f2bf(g - bf2f(hu));
        float g2 = gelu_exact(acc[8 + j]);
        ushort hu2 = f2bf(g2);
        hv1[j] = (short)hu2; lv1[j] = (short)f2bf(g2 - bf2f(hu2));
    }
    size_t base = (size_t)(px0 + tid) * D + h * CPH + c0;
    *(short8*)&o96h[base] = hv0;
    *(short8*)&o96h[base + 8] = hv1;
    *(short8*)&o96l[base] = lv0;
    *(short8*)&o96l[base + 8] = lv1;
}

// ---------------- K6: proj 1x1 as bf16x3 MFMA + nearest 2x upsample ----------
// R12: same single-barrier restructure as k_qkv_mfma.
__global__ __launch_bounds__(256) void k_proj_mfma(
    const ushort* __restrict__ wph, const ushort* __restrict__ wpl,
    const ushort* __restrict__ o96h, const ushort* __restrict__ o96l,
    const float* __restrict__ bp, float* __restrict__ out) {
    __shared__ ushort lds[2][4][4096];
    const int tid = threadIdx.x;
    const int lane = tid & 63, wid = tid >> 6;
    const int wm = wid >> 1, wn = wid & 1;

    const int d   = blockIdx.x;        // 0..215
    const int xcd = d & 7;
    const int idx = d >> 3;            // 0..26
    const int nt  = xcd * 9 + idx / 3; // n-tile 0..71
    const int ot  = idx % 3;           // o-tile 0..2
    const int o0 = ot * 128;
    const int n0 = nt * 128;

    const ushort* srcs[4];
    srcs[0] = wph + (size_t)o0 * D;
    srcs[1] = wpl + (size_t)o0 * D;
    srcs[2] = o96h + (size_t)n0 * D;
    srcs[3] = o96l + (size_t)n0 * D;

    f32x4 acc[4][4];
#pragma unroll
    for (int i = 0; i < 4; i++)
#pragma unroll
        for (int j = 0; j < 4; j++) acc[i][j] = (f32x4){0.f, 0.f, 0.f, 0.f};

    int a_off[4], b_off[4];
#pragma unroll
    for (int f = 0; f < 4; f++) {
        int ra = wm * 64 + f * 16 + (lane & 15);
        a_off[f] = ra * 64 + ((((lane >> 4) ^ ((ra >> 1) & 3)) & 3) << 4);
        int rb = wn * 64 + f * 16 + (lane & 15);
        b_off[f] = rb * 64 + ((((lane >> 4) ^ ((rb >> 1) & 3)) & 3) << 4);
    }

    auto STAGE = [&](int buf, int kk) {
#pragma unroll
        for (int i = 0; i < 8; i++) {
            const int mat = i >> 1;
            const int cm  = ((i & 1) << 2) | wid;
            const int row = cm * 16 + (lane >> 2);
            const int scol = (((lane & 3) ^ ((row >> 1) & 3)) & 3) << 4;
            const ushort* src = srcs[mat] + (size_t)row * D + kk + (scol >> 1);
            __builtin_amdgcn_global_load_lds(
                (const __attribute__((address_space(1))) void*)src,
                (__attribute__((address_space(3))) void*)&lds[buf][mat][cm * 512],
                16, 0, 0);
        }
    };

    STAGE(0, 0);
    for (int t = 0; t < 12; ++t) {
        const int cur = t & 1;
        asm volatile("s_waitcnt vmcnt(0)" ::: "memory");
        __builtin_amdgcn_s_barrier();
        if (t < 11) STAGE(cur ^ 1, (t + 1) * 32);

        const char* bA0 = (const char*)&lds[cur][0][0];
        const char* bA1 = (const char*)&lds[cur][1][0];
        const char* bB0 = (const char*)&lds[cur][2][0];
        const char* bB1 = (const char*)&lds[cur][3][0];
        short8 A[2][4], B[2][4];
#pragma unroll
        for (int f = 0; f < 4; f++) {
            A[0][f] = *(const short8*)(bA0 + a_off[f]);
            A[1][f] = *(const short8*)(bA1 + a_off[f]);
            B[0][f] = *(const short8*)(bB0 + b_off[f]);
            B[1][f] = *(const short8*)(bB1 + b_off[f]);
        }
        __builtin_amdgcn_s_setprio(1);
#pragma unroll
        for (int fm = 0; fm < 4; fm++)
#pragma unroll
            for (int fn = 0; fn < 4; fn++) {
                acc[fm][fn] = __builtin_amdgcn_mfma_f32_16x16x32_bf16(A[0][fm], B[0][fn], acc[fm][fn], 0, 0, 0);
                acc[fm][fn] = __builtin_amdgcn_mfma_f32_16x16x32_bf16(A[0][fm], B[1][fn], acc[fm][fn], 0, 0, 0);
                acc[fm][fn] = __builtin_amdgcn_mfma_f32_16x16x32_bf16(A[1][fm], B[0][fn], acc[fm][fn], 0, 0, 0);
            }
        __builtin_amdgcn_s_setprio(0);
    }

#pragma unroll
    for (int fn = 0; fn < 4; fn++) {
        const int n = n0 + wn * 64 + fn * 16 + (lane & 15);
        const int y = n / WP, xcol = n - y * WP;
        const size_t pbase = (size_t)(2 * y) * WFULL + 2 * xcol;
#pragma unroll
        for (int fm = 0; fm < 4; fm++) {
            f32x4 v = acc[fm][fn];
#pragma unroll
            for (int j = 0; j < 4; j++) {
                const int o = o0 + wm * 64 + fm * 16 + (lane >> 4) * 4 + j;
                const float val = v[j] + bp[o];
                float2 vv = make_float2(val, val);
                size_t base = (size_t)o * NF + pbase;
                *(float2*)&out[base] = vv;
                *(float2*)&out[base + WFULL] = vv;
            }
        }
    }
}

extern "C" void kernel_launch(void* const* d_in, const int* in_sizes, int n_in,
                              void* d_out, int out_size, void* d_ws, size_t ws_size,
                              hipStream_t stream) {
    (void)in_sizes; (void)n_in; (void)out_size; (void)ws_size;
    const float* x    = (const float*)d_in[0];
    const float* wq   = (const float*)d_in[1];
    const float* bq   = (const float*)d_in[2];
    const float* wd   = (const float*)d_in[3];
    const float* bd   = (const float*)d_in[4];
    const float* wp   = (const float*)d_in[5];
    const float* bp   = (const float*)d_in[6];
    const float* temp = (const float*)d_in[7];
    const float* a1   = (const float*)d_in[8];
    const float* a2   = (const float*)d_in[9];
    const float* a3   = (const float*)d_in[10];
    const float* a4   = (const float*)d_in[11];
    float* out = (float*)d_out;
    float* ws  = (float*)d_ws;

    // persistent region (44.4 MB high-water, proven R3-R11):
    float* pooled = ws;                       // 10,616,832 floats (42.5 MB)
    float* Wc     = ws + 10616832;            // 18,432
    ushort* wh    = (ushort*)(Wc + 18432 + 19200);  // 884,736 bf16 total
    ushort* wl    = wh + 442368;

    // carved out of pooled once pooled is dead (after dwconv):
    ushort* o96h   = (ushort*)ws;                              // 3,538,944 bf16
    ushort* o96l   = o96h + 3538944;                           // 3,538,944 bf16
    float*  Spart  = (float*)((char*)ws + 14155776);           // 884,736 f32
    float*  qnpart = Spart + 884736;                           // 18,432 f32
    float*  knpart = qnpart + 18432;                           // 18,432 f32
    ushort* wph    = (ushort*)(knpart + 18432);                // 147,456 bf16
    ushort* wpl    = wph + 147456;                             // 147,456 bf16

    float* qkvdw = out;                       // q,k,v after dw conv staged in d_out
    ushort* xh = (ushort*)d_out;              // x hi staged in d_out (dead pre-dwconv)
    ushort* xl = xh + 14155776;

    hipLaunchKernelGGL(k_prep,      dim3(3456),    dim3(256), 0, stream, wq, wh, wl, x, xh, xl);
    hipLaunchKernelGGL(k_qkv_mfma,  dim3(2592),    dim3(512), 0, stream, xh, xl, wh, wl, bq, pooled);
    hipLaunchKernelGGL(k_dwconv,    dim3(10368),   dim3(256), 0, stream, pooled, wd, bd, qkvdw);
    hipLaunchKernelGGL(k_prep_w,    dim3(576),     dim3(256), 0, stream, wp, wph, wpl, D * D);
    hipLaunchKernelGGL(k_attn_part, dim3(48, 8),   dim3(256), 0, stream, qkvdw, Spart, qnpart, knpart);
    hipLaunchKernelGGL(k_softmax,   dim3(96),      dim3(256), 0, stream, Spart, qnpart, knpart, temp, a1, a2, a3, a4, Wc);
    hipLaunchKernelGGL(k_av_gelu,   dim3(864),     dim3(256), 0, stream, qkvdw, Wc, o96h, o96l);
    hipLaunchKernelGGL(k_proj_mfma, dim3(216),     dim3(256), 0, stream, wph, wpl, o96h, o96l, bp, out);
}